// Round 4
// baseline (219.398 us; speedup 1.0000x reference)
//
#include <hip/hip_runtime.h>

typedef __attribute__((ext_vector_type(8))) short short8;
typedef __attribute__((ext_vector_type(4))) short short4v;
typedef __attribute__((ext_vector_type(8))) unsigned short u16x8;
typedef __attribute__((ext_vector_type(4))) float f32x4;

__device__ inline unsigned short f2bf(float f) {
  union { float f; unsigned int u; } v; v.f = f;
  unsigned int r = v.u + 0x7FFFu + ((v.u >> 16) & 1u);
  return (unsigned short)(r >> 16);
}

__device__ inline void gload_lds16(const void* g, void* l) {
  __builtin_amdgcn_global_load_lds(
      (const __attribute__((address_space(1))) unsigned int*)g,
      (__attribute__((address_space(3))) unsigned int*)l, 16, 0, 0);
}

// ---------------- conversion kernels ----------------

__global__ void cvt_bf16(const float4* __restrict__ in, ushort4* __restrict__ out) {
  const int i = blockIdx.x * blockDim.x + threadIdx.x;
  float4 v = in[i];
  ushort4 o;
  o.x = f2bf(v.x); o.y = f2bf(v.y); o.z = f2bf(v.z); o.w = f2bf(v.w);
  out[i] = o;
}

__global__ __launch_bounds__(256) void cvt_wT(const float* __restrict__ w,
                                              unsigned short* __restrict__ wT,
                                              float scale) {
  __shared__ float t[32][33];
  const int k0 = blockIdx.x * 32;
  const int n0 = blockIdx.y * 32;
  const int tx = threadIdx.x & 31, ty = threadIdx.x >> 5;  // 32 x 8
#pragma unroll
  for (int i = 0; i < 32; i += 8)
    t[ty + i][tx] = w[(size_t)(k0 + ty + i) * 1024 + n0 + tx];
  __syncthreads();
#pragma unroll
  for (int i = 0; i < 32; i += 8)
    wT[(size_t)(n0 + ty + i) * 1024 + k0 + tx] = f2bf(t[tx][ty + i] * scale);
}

__global__ void pack_bias(const float* __restrict__ bq, const float* __restrict__ bk,
                          const float* __restrict__ bv, float* __restrict__ out) {
  const int i = blockIdx.x * 256 + threadIdx.x;  // 0..3071
  float v;
  if (i < 1024) v = bq[i] * 0.18033688011f;  // 0.125 * log2(e): exp2-domain logits
  else if (i < 2048) v = bk[i - 1024];
  else v = bv[i - 2048];
  out[i] = v;
}

// ---------------- GEMM (m97 structure, unchanged) ----------------

template <typename OutT>
__global__ __launch_bounds__(256) void gemm_bt(
    const unsigned short* __restrict__ A, const unsigned short* __restrict__ Bt,
    const float* __restrict__ bias, OutT* __restrict__ C,
    int K, int ldc) {
  __shared__ unsigned short As[128 * 32];
  __shared__ unsigned short Bs[128 * 32];
  const int tid = threadIdx.x;
  const int lane = tid & 63;
  const int wave = tid >> 6;
  const int wm = (wave >> 1) * 64;
  const int wn = (wave & 1) * 64;
  const long bm = (long)blockIdx.x * 128;
  const long bn = (long)blockIdx.y * 128;

  const int sr = tid >> 2;
  const int sc = (tid & 3) * 8;
  const unsigned short* Ag0 = A + (bm + sr) * (long)K + sc;
  const unsigned short* Ag1 = A + (bm + 64 + sr) * (long)K + sc;
  const unsigned short* Bg0 = Bt + (bn + sr) * (long)K + sc;
  const unsigned short* Bg1 = Bt + (bn + 64 + sr) * (long)K + sc;
  unsigned short* As0 = &As[tid * 8];
  unsigned short* As1 = &As[2048 + tid * 8];
  unsigned short* Bs0 = &Bs[tid * 8];
  unsigned short* Bs1 = &Bs[2048 + tid * 8];

  f32x4 acc[4][4] = {};

  const int fr = lane & 15;
  const int fk = (lane >> 4) * 8;

  for (int kt = 0; kt < K; kt += 32) {
    gload_lds16(Ag0, As0);
    gload_lds16(Ag1, As1);
    gload_lds16(Bg0, Bs0);
    gload_lds16(Bg1, Bs1);
    Ag0 += 32; Ag1 += 32; Bg0 += 32; Bg1 += 32;
    __syncthreads();
    short8 af[4], bfv[4];
#pragma unroll
    for (int i = 0; i < 4; i++) af[i] = *(const short8*)&As[(wm + i * 16 + fr) * 32 + fk];
#pragma unroll
    for (int j = 0; j < 4; j++) bfv[j] = *(const short8*)&Bs[(wn + j * 16 + fr) * 32 + fk];
#pragma unroll
    for (int i = 0; i < 4; i++)
#pragma unroll
      for (int j = 0; j < 4; j++)
        acc[i][j] = __builtin_amdgcn_mfma_f32_16x16x32_bf16(af[i], bfv[j], acc[i][j], 0, 0, 0);
    __syncthreads();
  }

  const int crow = (lane >> 4) * 4;
  const int ccol = lane & 15;
#pragma unroll
  for (int j = 0; j < 4; j++) {
    const long col = bn + wn + j * 16 + ccol;
    const float bv = bias[col];
#pragma unroll
    for (int i = 0; i < 4; i++) {
#pragma unroll
      for (int r = 0; r < 4; r++) {
        const long row = bm + wm + i * 16 + crow + r;
        const float val = acc[i][j][r] + bv;
        if constexpr (__is_same(OutT, float)) C[row * ldc + col] = val;
        else                                  C[row * ldc + col] = f2bf(val);
      }
    }
  }
}

// ---------------- flash attention (v3: double-buffered, exp2, defer-max) ----------------
// QBLK=64 (4 waves x 16 q-rows), KVBLK=64, 2-phase pipeline (T3 minimum):
// STAGE(buf^1, t+1) issued BEFORE compute(buf) -> HBM latency hides under compute.
// K: XOR-chunk swizzle via pre-swizzled global_load_lds source (conflict-free both sides).
// V: [4][16]-subtiled for ds_read_b64_tr_b16 (verified r3: absmax unchanged, conflicts 0).
// Softmax in exp2 domain (0.125*log2e folded into wq/bq); defer-max THR=8 (T13).

#define TRRD(d, o) asm volatile("ds_read_b64_tr_b16 %0, %1 offset:" o \
                                : "=v"(d) : "v"(vtr) : "memory")

__global__ __launch_bounds__(256, 3) void attn_fwd(
    const unsigned short* __restrict__ qkv, unsigned short* __restrict__ out) {
  __shared__ unsigned short Ks[2 * 4096];
  __shared__ unsigned short Vs[2 * 4096];
  __shared__ unsigned short Ps[64 * 68];
  const int tid = threadIdx.x;
  const int lane = tid & 63;
  const int w = tid >> 6;

  // XCD-aware swizzle: xcd = blockIdx.x & 7 owns 4 (b,h) pairs x 32 qtiles
  const int xcd = blockIdx.x & 7, slot = blockIdx.x >> 3;  // slot 0..127
  const int pair = xcd * 4 + (slot >> 5);                  // 0..31
  const int qtile = slot & 31;
  const int h = pair & 15, b = pair >> 4;
  const long rowbase = (long)b * 2048;
  const int hq = h * 64;
  const int fr = lane & 15;
  const int fg = lane >> 4;
  const int fk = fg * 8;
  const int q0 = qtile * 64 + w * 16;

  // Q fragments in registers (pre-scaled by 0.125*log2e)
  short8 qf[2];
  {
    const long qr = rowbase + q0 + fr;
    qf[0] = *(const short8*)&qkv[qr * 3072 + hq + fk];
    qf[1] = *(const short8*)&qkv[qr * 3072 + hq + 32 + fk];
  }

  // K staging source (pre-swizzled): chunk row=c>>3, col-chunk=(tid&7)^(row&7)
  const int kr0 = tid >> 3, kr1 = 32 + (tid >> 3);
  const unsigned short* Kg0 = &qkv[(rowbase + kr0) * 3072 + 1024 + hq + (((tid & 7) ^ (kr0 & 7)) * 8)];
  const unsigned short* Kg1 = &qkv[(rowbase + kr1) * 3072 + 1024 + hq + (((tid & 7) ^ (kr1 & 7)) * 8)];
  // V staging source (decoded for [4][16]-subtiled tr_read layout)
  const int vkv0 = ((tid >> 3) & 3) * 8 + ((tid >> 5) & 1) * 4 + ((tid >> 1) & 3);
  const int vd0 = ((tid >> 6) & 3) * 16 + (tid & 1) * 8;
  const unsigned short* Vg0 = &qkv[(rowbase + vkv0) * 3072 + 2048 + hq + vd0];
  const unsigned short* Vg1 = &qkv[(rowbase + vkv0 + 32) * 3072 + 2048 + hq + vd0];

  auto stage = [&](int buf) {
    gload_lds16(Kg0, &Ks[buf * 4096 + tid * 8]);
    gload_lds16(Kg1, &Ks[buf * 4096 + 2048 + tid * 8]);
    gload_lds16(Vg0, &Vs[buf * 4096 + tid * 8]);
    gload_lds16(Vg1, &Vs[buf * 4096 + 2048 + tid * 8]);
    Kg0 += 64 * 3072; Kg1 += 64 * 3072; Vg0 += 64 * 3072; Vg1 += 64 * 3072;
  };

  f32x4 o[4] = {};
  float m_[4], s_[4];
#pragma unroll
  for (int r = 0; r < 4; r++) { m_[r] = -1e30f; s_[r] = 0.f; }

  stage(0);
  __syncthreads();  // tile 0 staged

  for (int t = 0; t < 32; t++) {
    const int cur = t & 1;
    if (t < 31) stage(cur ^ 1);  // prefetch next tile; latency hides under compute

    // QK^T from swizzled Ks[cur]
    short8 kf[4][2];
#pragma unroll
    for (int n = 0; n < 4; n++) {
      const int row = n * 16 + fr;
#pragma unroll
      for (int kc = 0; kc < 2; kc++) {
        const int idx = (row * 64 + kc * 32 + fk) ^ ((row & 7) << 3);
        kf[n][kc] = *(const short8*)&Ks[cur * 4096 + idx];
      }
    }
    f32x4 sa[4];
#pragma unroll
    for (int n = 0; n < 4; n++) {
      f32x4 z = {0.f, 0.f, 0.f, 0.f};
      z = __builtin_amdgcn_mfma_f32_16x16x32_bf16(qf[0], kf[n][0], z, 0, 0, 0);
      sa[n] = __builtin_amdgcn_mfma_f32_16x16x32_bf16(qf[1], kf[n][1], z, 0, 0, 0);
    }

    // online softmax (exp2 domain): lane holds rows fg*4+r, col n*16+fr
    float mx[4];
#pragma unroll
    for (int r = 0; r < 4; r++)
      mx[r] = fmaxf(fmaxf(sa[0][r], sa[1][r]), fmaxf(sa[2][r], sa[3][r]));
#pragma unroll
    for (int r = 0; r < 4; r++) {
      for (int off = 1; off < 16; off <<= 1) mx[r] = fmaxf(mx[r], __shfl_xor(mx[r], off));
    }
    // defer-max (T13): rescale only when tile max exceeds running max by >8
    const float g = fmaxf(fmaxf(mx[0] - m_[0], mx[1] - m_[1]),
                          fmaxf(mx[2] - m_[2], mx[3] - m_[3]));
    if (__any(g > 8.f)) {
#pragma unroll
      for (int r = 0; r < 4; r++) {
        const float nm = fmaxf(m_[r], mx[r]);
        const float fac = __builtin_amdgcn_exp2f(m_[r] - nm);
        m_[r] = nm;
        s_[r] *= fac;
#pragma unroll
        for (int dj = 0; dj < 4; dj++) o[dj][r] *= fac;
      }
    }
    float ps[4] = {0.f, 0.f, 0.f, 0.f};
    unsigned short pb[4][4];
#pragma unroll
    for (int n = 0; n < 4; n++)
#pragma unroll
      for (int r = 0; r < 4; r++) {
        const float p = __builtin_amdgcn_exp2f(sa[n][r] - m_[r]);
        ps[r] += p;
        pb[n][r] = f2bf(p);
      }
#pragma unroll
    for (int r = 0; r < 4; r++) {
      for (int off = 1; off < 16; off <<= 1) ps[r] += __shfl_xor(ps[r], off);
      s_[r] += ps[r];
    }
    // P -> LDS (wave-private rows)
#pragma unroll
    for (int n = 0; n < 4; n++)
#pragma unroll
      for (int r = 0; r < 4; r++)
        Ps[(w * 16 + fg * 4 + r) * 68 + n * 16 + fr] = pb[n][r];

    // PV
    short8 pa[2];
#pragma unroll
    for (int kc = 0; kc < 2; kc++)
      pa[kc] = *(const short8*)&Ps[(w * 16 + fr) * 68 + kc * 32 + fk];

    const __attribute__((address_space(3))) unsigned short* vtr =
        (const __attribute__((address_space(3))) unsigned short*)&Vs[0] + cur * 4096 + lane * 4;
    short4v v0[4][2], v1[4][2];
    TRRD(v0[0][0], "0");    TRRD(v1[0][0], "512");
    TRRD(v0[1][0], "1024"); TRRD(v1[1][0], "1536");
    TRRD(v0[2][0], "2048"); TRRD(v1[2][0], "2560");
    TRRD(v0[3][0], "3072"); TRRD(v1[3][0], "3584");
    TRRD(v0[0][1], "4096"); TRRD(v1[0][1], "4608");
    TRRD(v0[1][1], "5120"); TRRD(v1[1][1], "5632");
    TRRD(v0[2][1], "6144"); TRRD(v1[2][1], "6656");
    TRRD(v0[3][1], "7168"); TRRD(v1[3][1], "7680");
    asm volatile("s_waitcnt lgkmcnt(0)" ::: "memory");
    __builtin_amdgcn_sched_barrier(0);

#pragma unroll
    for (int dj = 0; dj < 4; dj++) {
#pragma unroll
      for (int kc = 0; kc < 2; kc++) {
        short8 vf = __builtin_shufflevector(v0[dj][kc], v1[dj][kc], 0, 1, 2, 3, 4, 5, 6, 7);
        o[dj] = __builtin_amdgcn_mfma_f32_16x16x32_bf16(pa[kc], vf, o[dj], 0, 0, 0);
      }
    }
    __syncthreads();  // drains vmcnt (next tile staged) + all reads of buf[cur] done
  }

#pragma unroll
  for (int dj = 0; dj < 4; dj++)
#pragma unroll
    for (int r = 0; r < 4; r++) {
      const long row = rowbase + q0 + fg * 4 + r;
      out[row * 1024 + hq + dj * 16 + fr] = f2bf(o[dj][r] / s_[r]);
    }
}

// ---------------- host ----------------

extern "C" void kernel_launch(void* const* d_in, const int* in_sizes, int n_in,
                              void* d_out, int out_size, void* d_ws, size_t ws_size,
                              hipStream_t stream) {
  const float* x  = (const float*)d_in[0];
  const float* wq = (const float*)d_in[1];
  const float* bq = (const float*)d_in[2];
  const float* wk = (const float*)d_in[3];
  const float* bk = (const float*)d_in[4];
  const float* wv = (const float*)d_in[5];
  const float* bv = (const float*)d_in[6];
  const float* wo = (const float*)d_in[7];
  const float* bo = (const float*)d_in[8];

  char* ws = (char*)d_ws;
  unsigned short* xb    = (unsigned short*)(ws);                       // 8 MB  [4096][1024]
  unsigned short* wqkvT = (unsigned short*)(ws + (8ull  << 20));       // 6 MB  [3072][1024]
  unsigned short* woT   = (unsigned short*)(ws + (14ull << 20));       // 2 MB  [1024][1024]
  float*          bqkv  = (float*)         (ws + (16ull << 20));       // 12 KB [3072]
  unsigned short* qkv   = (unsigned short*)(ws + (17ull << 20));       // 24 MB [4096][3072]
  unsigned short* attn  = (unsigned short*)(ws + (41ull << 20));       // 8 MB  [4096][1024]

  cvt_bf16<<<4096, 256, 0, stream>>>((const float4*)x, (ushort4*)xb);
  // Q path folded scale = 0.125 * log2(e) -> softmax runs in exp2 domain
  cvt_wT<<<dim3(32, 32), 256, 0, stream>>>(wq, wqkvT,                 0.18033688011f);
  cvt_wT<<<dim3(32, 32), 256, 0, stream>>>(wk, wqkvT + 1024 * 1024,   1.0f);
  cvt_wT<<<dim3(32, 32), 256, 0, stream>>>(wv, wqkvT + 2 * 1024 * 1024, 1.0f);
  cvt_wT<<<dim3(32, 32), 256, 0, stream>>>(wo, woT,                   1.0f);
  pack_bias<<<12, 256, 0, stream>>>(bq, bk, bv, bqkv);

  gemm_bt<unsigned short><<<dim3(32, 24), 256, 0, stream>>>(xb, wqkvT, bqkv, qkv, 1024, 3072);

  attn_fwd<<<1024, 256, 0, stream>>>(qkv, attn);

  gemm_bt<float><<<dim3(32, 8), 256, 0, stream>>>(attn, woT, bo, (float*)d_out, 1024, 1024);
}

// Round 5
// 157.906 us; speedup vs baseline: 1.3894x; 1.3894x over previous
//
#include <hip/hip_runtime.h>

typedef __attribute__((ext_vector_type(8))) short short8;
typedef __attribute__((ext_vector_type(4))) short short4v;
typedef __attribute__((ext_vector_type(8))) unsigned short u16x8;
typedef __attribute__((ext_vector_type(4))) float f32x4;

__device__ inline unsigned short f2bf(float f) {
  union { float f; unsigned int u; } v; v.f = f;
  unsigned int r = v.u + 0x7FFFu + ((v.u >> 16) & 1u);
  return (unsigned short)(r >> 16);
}

__device__ inline unsigned short f2bf_trunc(float f) {
  union { float f; unsigned int u; } v; v.f = f;
  return (unsigned short)(v.u >> 16);
}

__device__ inline void gload_lds16(const void* g, void* l) {
  __builtin_amdgcn_global_load_lds(
      (const __attribute__((address_space(1))) unsigned int*)g,
      (__attribute__((address_space(3))) unsigned int*)l, 16, 0, 0);
}

// ---------------- conversion kernels ----------------

__global__ void cvt_bf16(const float4* __restrict__ in, ushort4* __restrict__ out) {
  const int i = blockIdx.x * blockDim.x + threadIdx.x;
  float4 v = in[i];
  ushort4 o;
  o.x = f2bf(v.x); o.y = f2bf(v.y); o.z = f2bf(v.z); o.w = f2bf(v.w);
  out[i] = o;
}

__global__ __launch_bounds__(256) void cvt_wT(const float* __restrict__ w,
                                              unsigned short* __restrict__ wT,
                                              float scale) {
  __shared__ float t[32][33];
  const int k0 = blockIdx.x * 32;
  const int n0 = blockIdx.y * 32;
  const int tx = threadIdx.x & 31, ty = threadIdx.x >> 5;  // 32 x 8
#pragma unroll
  for (int i = 0; i < 32; i += 8)
    t[ty + i][tx] = w[(size_t)(k0 + ty + i) * 1024 + n0 + tx];
  __syncthreads();
#pragma unroll
  for (int i = 0; i < 32; i += 8)
    wT[(size_t)(n0 + ty + i) * 1024 + k0 + tx] = f2bf(t[tx][ty + i] * scale);
}

__global__ void pack_bias(const float* __restrict__ bq, const float* __restrict__ bk,
                          const float* __restrict__ bv, float* __restrict__ out) {
  const int i = blockIdx.x * 256 + threadIdx.x;  // 0..3071
  float v;
  if (i < 1024) v = bq[i] * 0.18033688011f;  // 0.125 * log2(e): exp2-domain logits
  else if (i < 2048) v = bk[i - 1024];
  else v = bv[i - 2048];
  out[i] = v;
}

// ---------------- GEMM (m97 structure, unchanged) ----------------

template <typename OutT>
__global__ __launch_bounds__(256) void gemm_bt(
    const unsigned short* __restrict__ A, const unsigned short* __restrict__ Bt,
    const float* __restrict__ bias, OutT* __restrict__ C,
    int K, int ldc) {
  __shared__ unsigned short As[128 * 32];
  __shared__ unsigned short Bs[128 * 32];
  const int tid = threadIdx.x;
  const int lane = tid & 63;
  const int wave = tid >> 6;
  const int wm = (wave >> 1) * 64;
  const int wn = (wave & 1) * 64;
  const long bm = (long)blockIdx.x * 128;
  const long bn = (long)blockIdx.y * 128;

  const int sr = tid >> 2;
  const int sc = (tid & 3) * 8;
  const unsigned short* Ag0 = A + (bm + sr) * (long)K + sc;
  const unsigned short* Ag1 = A + (bm + 64 + sr) * (long)K + sc;
  const unsigned short* Bg0 = Bt + (bn + sr) * (long)K + sc;
  const unsigned short* Bg1 = Bt + (bn + 64 + sr) * (long)K + sc;
  unsigned short* As0 = &As[tid * 8];
  unsigned short* As1 = &As[2048 + tid * 8];
  unsigned short* Bs0 = &Bs[tid * 8];
  unsigned short* Bs1 = &Bs[2048 + tid * 8];

  f32x4 acc[4][4] = {};

  const int fr = lane & 15;
  const int fk = (lane >> 4) * 8;

  for (int kt = 0; kt < K; kt += 32) {
    gload_lds16(Ag0, As0);
    gload_lds16(Ag1, As1);
    gload_lds16(Bg0, Bs0);
    gload_lds16(Bg1, Bs1);
    Ag0 += 32; Ag1 += 32; Bg0 += 32; Bg1 += 32;
    __syncthreads();
    short8 af[4], bfv[4];
#pragma unroll
    for (int i = 0; i < 4; i++) af[i] = *(const short8*)&As[(wm + i * 16 + fr) * 32 + fk];
#pragma unroll
    for (int j = 0; j < 4; j++) bfv[j] = *(const short8*)&Bs[(wn + j * 16 + fr) * 32 + fk];
#pragma unroll
    for (int i = 0; i < 4; i++)
#pragma unroll
      for (int j = 0; j < 4; j++)
        acc[i][j] = __builtin_amdgcn_mfma_f32_16x16x32_bf16(af[i], bfv[j], acc[i][j], 0, 0, 0);
    __syncthreads();
  }

  const int crow = (lane >> 4) * 4;
  const int ccol = lane & 15;
#pragma unroll
  for (int j = 0; j < 4; j++) {
    const long col = bn + wn + j * 16 + ccol;
    const float bv = bias[col];
#pragma unroll
    for (int i = 0; i < 4; i++) {
#pragma unroll
      for (int r = 0; r < 4; r++) {
        const long row = bm + wm + i * 16 + crow + r;
        const float val = acc[i][j][r] + bv;
        if constexpr (__is_same(OutT, float)) C[row * ldc + col] = val;
        else                                  C[row * ldc + col] = f2bf(val);
      }
    }
  }
}

// ---------------- flash attention (v4) ----------------
// QBLK=64 (4 waves x 16 q-rows), KVBLK=64, 2-phase double-buffered pipeline.
// LDS = 16K(K,2buf) + 16K(V,2buf) + 8K(P) = 40960 B exactly -> 4 blocks/CU.
// K: XOR-chunk swizzle via pre-swizzled global_load_lds source (verified r3/r4).
// V: [4][16]-subtiled for ds_read_b64_tr_b16 (verified r3/r4).
// P: stride 64 + XOR swizzle (col ^= (row&7)<<3) -> b128 reads at min aliasing.
// Softmax: exp2 domain, defer-max gate (__any on local max), row-sum via
// mfma(P, ones) accumulated alongside O (removes all sum shuffles).

#define TRRD(d, o) asm volatile("ds_read_b64_tr_b16 %0, %1 offset:" o \
                                : "=v"(d) : "v"(vtr) : "memory")

__global__ __launch_bounds__(256, 4) void attn_fwd(
    const unsigned short* __restrict__ qkv, unsigned short* __restrict__ out) {
  __shared__ unsigned short Ks[2 * 4096];
  __shared__ unsigned short Vs[2 * 4096];
  __shared__ unsigned short Ps[64 * 64];
  const int tid = threadIdx.x;
  const int lane = tid & 63;
  const int w = tid >> 6;

  // XCD-aware swizzle: xcd = blockIdx.x & 7 owns 4 (b,h) pairs x 32 qtiles
  const int xcd = blockIdx.x & 7, slot = blockIdx.x >> 3;  // slot 0..127
  const int pair = xcd * 4 + (slot >> 5);                  // 0..31
  const int qtile = slot & 31;
  const int h = pair & 15, b = pair >> 4;
  const long rowbase = (long)b * 2048;
  const int hq = h * 64;
  const int fr = lane & 15;
  const int fg = lane >> 4;
  const int fk = fg * 8;
  const int q0 = qtile * 64 + w * 16;

  // Q fragments in registers (pre-scaled by 0.125*log2e)
  short8 qf[2];
  {
    const long qr = rowbase + q0 + fr;
    qf[0] = *(const short8*)&qkv[qr * 3072 + hq + fk];
    qf[1] = *(const short8*)&qkv[qr * 3072 + hq + 32 + fk];
  }

  // K staging source (pre-swizzled): chunk row=c>>3, col-chunk=(tid&7)^(row&7)
  const int kr0 = tid >> 3, kr1 = 32 + (tid >> 3);
  const unsigned short* Kg0 = &qkv[(rowbase + kr0) * 3072 + 1024 + hq + (((tid & 7) ^ (kr0 & 7)) * 8)];
  const unsigned short* Kg1 = &qkv[(rowbase + kr1) * 3072 + 1024 + hq + (((tid & 7) ^ (kr1 & 7)) * 8)];
  // V staging source (decoded for [4][16]-subtiled tr_read layout)
  const int vkv0 = ((tid >> 3) & 3) * 8 + ((tid >> 5) & 1) * 4 + ((tid >> 1) & 3);
  const int vd0 = ((tid >> 6) & 3) * 16 + (tid & 1) * 8;
  const unsigned short* Vg0 = &qkv[(rowbase + vkv0) * 3072 + 2048 + hq + vd0];
  const unsigned short* Vg1 = &qkv[(rowbase + vkv0 + 32) * 3072 + 2048 + hq + vd0];

  auto stage = [&](int buf) {
    gload_lds16(Kg0, &Ks[buf * 4096 + tid * 8]);
    gload_lds16(Kg1, &Ks[buf * 4096 + 2048 + tid * 8]);
    gload_lds16(Vg0, &Vs[buf * 4096 + tid * 8]);
    gload_lds16(Vg1, &Vs[buf * 4096 + 2048 + tid * 8]);
    Kg0 += 64 * 3072; Kg1 += 64 * 3072; Vg0 += 64 * 3072; Vg1 += 64 * 3072;
  };

  short8 onesv;
#pragma unroll
  for (int e = 0; e < 8; e++) onesv[e] = (short)0x3F80;  // bf16 1.0

  f32x4 o[4] = {};
  f32x4 s_acc = {0.f, 0.f, 0.f, 0.f};
  float m_[4];
#pragma unroll
  for (int r = 0; r < 4; r++) m_[r] = -1e30f;

  stage(0);
  __syncthreads();  // tile 0 staged

  for (int t = 0; t < 32; t++) {
    const int cur = t & 1;
    if (t < 31) stage(cur ^ 1);  // prefetch next tile; latency hides under compute

    // QK^T from swizzled Ks[cur]
    short8 kf[4][2];
#pragma unroll
    for (int n = 0; n < 4; n++) {
      const int row = n * 16 + fr;
#pragma unroll
      for (int kc = 0; kc < 2; kc++) {
        const int idx = (row * 64 + kc * 32 + fk) ^ ((row & 7) << 3);
        kf[n][kc] = *(const short8*)&Ks[cur * 4096 + idx];
      }
    }
    f32x4 sa[4];
#pragma unroll
    for (int n = 0; n < 4; n++) {
      f32x4 z = {0.f, 0.f, 0.f, 0.f};
      z = __builtin_amdgcn_mfma_f32_16x16x32_bf16(qf[0], kf[n][0], z, 0, 0, 0);
      sa[n] = __builtin_amdgcn_mfma_f32_16x16x32_bf16(qf[1], kf[n][1], z, 0, 0, 0);
    }

    // defer-max gate: cheap per-lane bound, full reduce+rescale only when needed.
    // rowmax_r - m_[r] <= lmax - mmin <= 8 guarantees P = exp2(sa - m_) <= 2^8.
    float lmax;
    {
      float a0 = fmaxf(fmaxf(sa[0][0], sa[0][1]), fmaxf(sa[0][2], sa[0][3]));
      float a1 = fmaxf(fmaxf(sa[1][0], sa[1][1]), fmaxf(sa[1][2], sa[1][3]));
      float a2 = fmaxf(fmaxf(sa[2][0], sa[2][1]), fmaxf(sa[2][2], sa[2][3]));
      float a3 = fmaxf(fmaxf(sa[3][0], sa[3][1]), fmaxf(sa[3][2], sa[3][3]));
      lmax = fmaxf(fmaxf(a0, a1), fmaxf(a2, a3));
    }
    const float mmin = fminf(fminf(m_[0], m_[1]), fminf(m_[2], m_[3]));
    if (__any(lmax - mmin > 8.f)) {
      float mx[4];
#pragma unroll
      for (int r = 0; r < 4; r++)
        mx[r] = fmaxf(fmaxf(sa[0][r], sa[1][r]), fmaxf(sa[2][r], sa[3][r]));
#pragma unroll
      for (int r = 0; r < 4; r++) {
        for (int off = 1; off < 16; off <<= 1) mx[r] = fmaxf(mx[r], __shfl_xor(mx[r], off));
      }
#pragma unroll
      for (int r = 0; r < 4; r++) {
        const float nm = fmaxf(m_[r], mx[r]);
        const float fac = __builtin_amdgcn_exp2f(m_[r] - nm);
        m_[r] = nm;
        s_acc[r] *= fac;
#pragma unroll
        for (int dj = 0; dj < 4; dj++) o[dj][r] *= fac;
      }
    }

    // P = exp2(sa - m_) -> truncated bf16 -> swizzled Ps (stride 64)
#pragma unroll
    for (int n = 0; n < 4; n++)
#pragma unroll
      for (int r = 0; r < 4; r++) {
        const float p = __builtin_amdgcn_exp2f(sa[n][r] - m_[r]);
        const int row = w * 16 + fg * 4 + r;
        const int col = (n * 16 + fr) ^ (((fg * 4 + r) & 7) << 3);
        Ps[row * 64 + col] = f2bf_trunc(p);
      }

    // P A-fragments (same-wave rows; swizzled read)
    short8 pa[2];
#pragma unroll
    for (int kc = 0; kc < 2; kc++)
      pa[kc] = *(const short8*)&Ps[(w * 16 + fr) * 64 + ((kc * 32 + fk) ^ ((fr & 7) << 3))];

    // row-sum via MFMA: s_acc[r] += sum_kv P[q=fg*4+r][kv]  (every col identical)
    s_acc = __builtin_amdgcn_mfma_f32_16x16x32_bf16(pa[0], onesv, s_acc, 0, 0, 0);
    s_acc = __builtin_amdgcn_mfma_f32_16x16x32_bf16(pa[1], onesv, s_acc, 0, 0, 0);

    // V^T B-fragments via HW transpose read
    const __attribute__((address_space(3))) unsigned short* vtr =
        (const __attribute__((address_space(3))) unsigned short*)&Vs[0] + cur * 4096 + lane * 4;
    short4v v0[4][2], v1[4][2];
    TRRD(v0[0][0], "0");    TRRD(v1[0][0], "512");
    TRRD(v0[1][0], "1024"); TRRD(v1[1][0], "1536");
    TRRD(v0[2][0], "2048"); TRRD(v1[2][0], "2560");
    TRRD(v0[3][0], "3072"); TRRD(v1[3][0], "3584");
    TRRD(v0[0][1], "4096"); TRRD(v1[0][1], "4608");
    TRRD(v0[1][1], "5120"); TRRD(v1[1][1], "5632");
    TRRD(v0[2][1], "6144"); TRRD(v1[2][1], "6656");
    TRRD(v0[3][1], "7168"); TRRD(v1[3][1], "7680");
    asm volatile("s_waitcnt lgkmcnt(0)" ::: "memory");
    __builtin_amdgcn_sched_barrier(0);

#pragma unroll
    for (int dj = 0; dj < 4; dj++) {
#pragma unroll
      for (int kc = 0; kc < 2; kc++) {
        short8 vf = __builtin_shufflevector(v0[dj][kc], v1[dj][kc], 0, 1, 2, 3, 4, 5, 6, 7);
        o[dj] = __builtin_amdgcn_mfma_f32_16x16x32_bf16(pa[kc], vf, o[dj], 0, 0, 0);
      }
    }
    __syncthreads();  // drains vmcnt (next tile staged) + all reads of buf[cur] done
  }

  float rs[4];
#pragma unroll
  for (int r = 0; r < 4; r++) rs[r] = __builtin_amdgcn_rcpf(s_acc[r]);
#pragma unroll
  for (int dj = 0; dj < 4; dj++)
#pragma unroll
    for (int r = 0; r < 4; r++) {
      const long row = rowbase + q0 + fg * 4 + r;
      out[row * 1024 + hq + dj * 16 + fr] = f2bf(o[dj][r] * rs[r]);
    }
}

// ---------------- host ----------------

extern "C" void kernel_launch(void* const* d_in, const int* in_sizes, int n_in,
                              void* d_out, int out_size, void* d_ws, size_t ws_size,
                              hipStream_t stream) {
  const float* x  = (const float*)d_in[0];
  const float* wq = (const float*)d_in[1];
  const float* bq = (const float*)d_in[2];
  const float* wk = (const float*)d_in[3];
  const float* bk = (const float*)d_in[4];
  const float* wv = (const float*)d_in[5];
  const float* bv = (const float*)d_in[6];
  const float* wo = (const float*)d_in[7];
  const float* bo = (const float*)d_in[8];

  char* ws = (char*)d_ws;
  unsigned short* xb    = (unsigned short*)(ws);                       // 8 MB  [4096][1024]
  unsigned short* wqkvT = (unsigned short*)(ws + (8ull  << 20));       // 6 MB  [3072][1024]
  unsigned short* woT   = (unsigned short*)(ws + (14ull << 20));       // 2 MB  [1024][1024]
  float*          bqkv  = (float*)         (ws + (16ull << 20));       // 12 KB [3072]
  unsigned short* qkv   = (unsigned short*)(ws + (17ull << 20));       // 24 MB [4096][3072]
  unsigned short* attn  = (unsigned short*)(ws + (41ull << 20));       // 8 MB  [4096][1024]

  cvt_bf16<<<4096, 256, 0, stream>>>((const float4*)x, (ushort4*)xb);
  // Q path folded scale = 0.125 * log2(e) -> softmax runs in exp2 domain
  cvt_wT<<<dim3(32, 32), 256, 0, stream>>>(wq, wqkvT,                 0.18033688011f);
  cvt_wT<<<dim3(32, 32), 256, 0, stream>>>(wk, wqkvT + 1024 * 1024,   1.0f);
  cvt_wT<<<dim3(32, 32), 256, 0, stream>>>(wv, wqkvT + 2 * 1024 * 1024, 1.0f);
  cvt_wT<<<dim3(32, 32), 256, 0, stream>>>(wo, woT,                   1.0f);
  pack_bias<<<12, 256, 0, stream>>>(bq, bk, bv, bqkv);

  gemm_bt<unsigned short><<<dim3(32, 24), 256, 0, stream>>>(xb, wqkvT, bqkv, qkv, 1024, 3072);

  attn_fwd<<<1024, 256, 0, stream>>>(qkv, attn);

  gemm_bt<float><<<dim3(32, 8), 256, 0, stream>>>(attn, woT, bo, (float*)d_out, 1024, 1024);
}

// Round 6
// 136.237 us; speedup vs baseline: 1.6104x; 1.1591x over previous
//
#include <hip/hip_runtime.h>

typedef __attribute__((ext_vector_type(8))) short short8;
typedef __attribute__((ext_vector_type(4))) short short4v;
typedef __attribute__((ext_vector_type(8))) unsigned short u16x8;
typedef __attribute__((ext_vector_type(4))) float f32x4;

__device__ inline unsigned short f2bf(float f) {
  union { float f; unsigned int u; } v; v.f = f;
  unsigned int r = v.u + 0x7FFFu + ((v.u >> 16) & 1u);
  return (unsigned short)(r >> 16);
}

__device__ inline unsigned short f2bf_trunc(float f) {
  union { float f; unsigned int u; } v; v.f = f;
  return (unsigned short)(v.u >> 16);
}

__device__ inline void gload_lds16(const void* g, void* l) {
  __builtin_amdgcn_global_load_lds(
      (const __attribute__((address_space(1))) unsigned int*)g,
      (__attribute__((address_space(3))) unsigned int*)l, 16, 0, 0);
}

// ---------------- conversion kernels ----------------

__global__ void cvt_bf16(const float4* __restrict__ in, ushort4* __restrict__ out) {
  const int i = blockIdx.x * blockDim.x + threadIdx.x;
  float4 v = in[i];
  ushort4 o;
  o.x = f2bf(v.x); o.y = f2bf(v.y); o.z = f2bf(v.z); o.w = f2bf(v.w);
  out[i] = o;
}

// all four weight transposes in one launch (z = 0..3 -> wq,wk,wv,wo)
__global__ __launch_bounds__(256) void cvt_wT_all(
    const float* __restrict__ wq, const float* __restrict__ wk,
    const float* __restrict__ wv, const float* __restrict__ wo,
    unsigned short* __restrict__ wqkvT, unsigned short* __restrict__ woT) {
  const int z = blockIdx.z;
  const float* w = (z == 0) ? wq : (z == 1) ? wk : (z == 2) ? wv : wo;
  unsigned short* dst = (z < 3) ? (wqkvT + (size_t)z * 1024 * 1024) : woT;
  const float scale = (z == 0) ? 0.18033688011f : 1.0f;  // 0.125*log2(e) on Q path
  __shared__ float t[32][33];
  const int k0 = blockIdx.x * 32;
  const int n0 = blockIdx.y * 32;
  const int tx = threadIdx.x & 31, ty = threadIdx.x >> 5;  // 32 x 8
#pragma unroll
  for (int i = 0; i < 32; i += 8)
    t[ty + i][tx] = w[(size_t)(k0 + ty + i) * 1024 + n0 + tx];
  __syncthreads();
#pragma unroll
  for (int i = 0; i < 32; i += 8)
    dst[(size_t)(n0 + ty + i) * 1024 + k0 + tx] = f2bf(t[tx][ty + i] * scale);
}

__global__ void pack_bias(const float* __restrict__ bq, const float* __restrict__ bk,
                          const float* __restrict__ bv, float* __restrict__ out) {
  const int i = blockIdx.x * 256 + threadIdx.x;  // 0..3071
  float v;
  if (i < 1024) v = bq[i] * 0.18033688011f;
  else if (i < 2048) v = bk[i - 1024];
  else v = bv[i - 2048];
  out[i] = v;
}

// ---------------- GEMM 128^2 (m97 structure) — used for O-projection ----------------

template <typename OutT>
__global__ __launch_bounds__(256) void gemm_bt(
    const unsigned short* __restrict__ A, const unsigned short* __restrict__ Bt,
    const float* __restrict__ bias, OutT* __restrict__ C,
    int K, int ldc) {
  __shared__ unsigned short As[128 * 32];
  __shared__ unsigned short Bs[128 * 32];
  const int tid = threadIdx.x;
  const int lane = tid & 63;
  const int wave = tid >> 6;
  const int wm = (wave >> 1) * 64;
  const int wn = (wave & 1) * 64;
  const long bm = (long)blockIdx.x * 128;
  const long bn = (long)blockIdx.y * 128;

  const int sr = tid >> 2;
  const int sc = (tid & 3) * 8;
  const unsigned short* Ag0 = A + (bm + sr) * (long)K + sc;
  const unsigned short* Ag1 = A + (bm + 64 + sr) * (long)K + sc;
  const unsigned short* Bg0 = Bt + (bn + sr) * (long)K + sc;
  const unsigned short* Bg1 = Bt + (bn + 64 + sr) * (long)K + sc;
  unsigned short* As0 = &As[tid * 8];
  unsigned short* As1 = &As[2048 + tid * 8];
  unsigned short* Bs0 = &Bs[tid * 8];
  unsigned short* Bs1 = &Bs[2048 + tid * 8];

  f32x4 acc[4][4] = {};

  const int fr = lane & 15;
  const int fk = (lane >> 4) * 8;

  for (int kt = 0; kt < K; kt += 32) {
    gload_lds16(Ag0, As0);
    gload_lds16(Ag1, As1);
    gload_lds16(Bg0, Bs0);
    gload_lds16(Bg1, Bs1);
    Ag0 += 32; Ag1 += 32; Bg0 += 32; Bg1 += 32;
    __syncthreads();
    short8 af[4], bfv[4];
#pragma unroll
    for (int i = 0; i < 4; i++) af[i] = *(const short8*)&As[(wm + i * 16 + fr) * 32 + fk];
#pragma unroll
    for (int j = 0; j < 4; j++) bfv[j] = *(const short8*)&Bs[(wn + j * 16 + fr) * 32 + fk];
#pragma unroll
    for (int i = 0; i < 4; i++)
#pragma unroll
      for (int j = 0; j < 4; j++)
        acc[i][j] = __builtin_amdgcn_mfma_f32_16x16x32_bf16(af[i], bfv[j], acc[i][j], 0, 0, 0);
    __syncthreads();
  }

  const int crow = (lane >> 4) * 4;
  const int ccol = lane & 15;
#pragma unroll
  for (int j = 0; j < 4; j++) {
    const long col = bn + wn + j * 16 + ccol;
    const float bv = bias[col];
#pragma unroll
    for (int i = 0; i < 4; i++) {
#pragma unroll
      for (int r = 0; r < 4; r++) {
        const long row = bm + wm + i * 16 + crow + r;
        const float val = acc[i][j][r] + bv;
        if constexpr (__is_same(OutT, float)) C[row * ldc + col] = val;
        else                                  C[row * ldc + col] = f2bf(val);
      }
    }
  }
}

// ---------------- GEMM 256^2, BK=64, 8 waves, 8-phase counted-vmcnt ----------------
// K fixed = 1024 (16 K-tiles, 8 iterations x 2 K-tiles). LDS 128KB (2 buf x (A 32K + B 32K)).
// Schedule (derived; safety: stages only target regions freed at an earlier lgkmcnt(0)):
//   p1: read all B-frags(T)+A mi0-1; stage A0,A1(T+1)->buf1      [4 loads]
//   p2: A mi2-3; stage B0(T+2)->buf0                             [2]
//   p3: A mi4-5; stage B1(T+2)->buf0                             [2]
//   p4: A mi6-7; gate vmcnt(4) (A(T+1),B(T+1) landed)
//   p5-p8: same with buf1/tile T+1, staging A(T+2)->buf0, B(T+3)->buf1, gate vmcnt(4)
// Both-sides XOR swizzle (chunk ^= row&7) — same scheme as attn K (measured 0 conflicts).

__global__ __launch_bounds__(512, 2) void gemm256(
    const unsigned short* __restrict__ A, const unsigned short* __restrict__ Bt,
    const float* __restrict__ bias, unsigned short* __restrict__ C, int ldc) {
  constexpr int K = 1024;
  __shared__ unsigned short Sab[2][2][16384];  // [buf][0=A,1=B][256*64]
  const int tid = threadIdx.x;
  const int lane = tid & 63;
  const int w = tid >> 6;
  const int wr = w >> 2, wc = w & 3;
  const long bm = (long)blockIdx.x * 256;
  const long bn = (long)blockIdx.y * 256;
  const int fr = lane & 15, fg = lane >> 4;

  const int srow = tid >> 3;  // 0..63
  const int kch = tid & 7;

  auto stage = [&](int o, int buf, int tk, int h) {
#pragma unroll
    for (int l = 0; l < 2; ++l) {
      const int rih = l * 64 + srow;  // row in half 0..127
      const unsigned short* src = (o ? Bt : A) +
          ((o ? bn : bm) + h * 128 + rih) * (long)K + tk * 64 + ((kch ^ (rih & 7)) * 8);
      gload_lds16(src, &Sab[buf][o][h * 8192 + (l * 512 + tid) * 8]);
    }
  };

  f32x4 acc[8][4] = {};

  // prologue: A(0),B(0) -> buf0; B(1) -> buf1
  stage(0, 0, 0, 0); stage(0, 0, 0, 1);
  stage(1, 0, 0, 0); stage(1, 0, 0, 1);
  stage(1, 1, 1, 0); stage(1, 1, 1, 1);
  asm volatile("s_waitcnt vmcnt(4)" ::: "memory");  // A(0),B(0) landed
  __builtin_amdgcn_s_barrier();

  for (int it = 0; it < 8; ++it) {
    const int T = 2 * it;
    const int tkA = (T + 2 < 15) ? T + 2 : 15;  // clamped prefetch tiles (uniform vmcnt)
    const int tkB3 = (T + 3 < 15) ? T + 3 : 15;
#pragma unroll
    for (int half = 0; half < 2; ++half) {
      const int b = half;
      short8 bfr[4][2];
      short8 afr[2][2];
#pragma unroll
      for (int g = 0; g < 4; ++g) {
        // 1) ds_reads for this phase
        if (g == 0) {
#pragma unroll
          for (int nj = 0; nj < 4; ++nj)
#pragma unroll
            for (int kc = 0; kc < 2; ++kc) {
              const int r = wc * 64 + nj * 16 + fr;
              bfr[nj][kc] = *(const short8*)&Sab[b][1][r * 64 + ((kc * 4 + fg) ^ (r & 7)) * 8];
            }
        }
#pragma unroll
        for (int mil = 0; mil < 2; ++mil)
#pragma unroll
          for (int kc = 0; kc < 2; ++kc) {
            const int r = wr * 128 + (2 * g + mil) * 16 + fr;
            afr[mil][kc] = *(const short8*)&Sab[b][0][r * 64 + ((kc * 4 + fg) ^ (r & 7)) * 8];
          }
        // 2) stage per schedule
        if (half == 0) {
          if (g == 0)      { stage(0, 1, T + 1, 0); stage(0, 1, T + 1, 1); }
          else if (g == 1) { stage(1, 0, tkA, 0); }
          else if (g == 2) { stage(1, 0, tkA, 1); }
        } else {
          if (g == 0)      { stage(0, 0, tkA, 0); stage(0, 0, tkA, 1); }
          else if (g == 1) { stage(1, 1, tkB3, 0); }
          else if (g == 2) { stage(1, 1, tkB3, 1); }
        }
        // 3) barrier; 4) wait ds_reads
        __builtin_amdgcn_s_barrier();
        asm volatile("s_waitcnt lgkmcnt(0)" ::: "memory");
        __builtin_amdgcn_sched_barrier(0);
        // 5) 16 MFMA (C-quadrant x K=64)
        __builtin_amdgcn_s_setprio(1);
#pragma unroll
        for (int mil = 0; mil < 2; ++mil)
#pragma unroll
          for (int nj = 0; nj < 4; ++nj)
#pragma unroll
            for (int kc = 0; kc < 2; ++kc)
              acc[2 * g + mil][nj] = __builtin_amdgcn_mfma_f32_16x16x32_bf16(
                  afr[mil][kc], bfr[nj][kc], acc[2 * g + mil][nj], 0, 0, 0);
        __builtin_amdgcn_s_setprio(0);
        // 6) counted gate once per K-tile
        if (g == 3) asm volatile("s_waitcnt vmcnt(4)" ::: "memory");
        // 7) barrier
        __builtin_amdgcn_s_barrier();
      }
    }
  }

  const int crow = fg * 4;
  const int ccol = fr;
#pragma unroll
  for (int nj = 0; nj < 4; ++nj) {
    const long col = bn + wc * 64 + nj * 16 + ccol;
    const float bv = bias[col];
#pragma unroll
    for (int mi = 0; mi < 8; ++mi)
#pragma unroll
      for (int r = 0; r < 4; ++r) {
        const long row = bm + wr * 128 + mi * 16 + crow + r;
        C[row * ldc + col] = f2bf(acc[mi][nj][r] + bv);
      }
  }
}

// ---------------- flash attention (v5: + tr-read interleave, setprio) ----------------

#define TRRD(d, o) asm volatile("ds_read_b64_tr_b16 %0, %1 offset:" o \
                                : "=v"(d) : "v"(vtr) : "memory")
#define LGKM(n) asm volatile("s_waitcnt lgkmcnt(" #n ")" ::: "memory")

__global__ __launch_bounds__(256, 4) void attn_fwd(
    const unsigned short* __restrict__ qkv, unsigned short* __restrict__ out) {
  __shared__ unsigned short Ks[2 * 4096];
  __shared__ unsigned short Vs[2 * 4096];
  __shared__ unsigned short Ps[64 * 64];
  const int tid = threadIdx.x;
  const int lane = tid & 63;
  const int w = tid >> 6;

  const int xcd = blockIdx.x & 7, slot = blockIdx.x >> 3;
  const int pair = xcd * 4 + (slot >> 5);
  const int qtile = slot & 31;
  const int h = pair & 15, b = pair >> 4;
  const long rowbase = (long)b * 2048;
  const int hq = h * 64;
  const int fr = lane & 15;
  const int fg = lane >> 4;
  const int fk = fg * 8;
  const int q0 = qtile * 64 + w * 16;

  short8 qf[2];
  {
    const long qr = rowbase + q0 + fr;
    qf[0] = *(const short8*)&qkv[qr * 3072 + hq + fk];
    qf[1] = *(const short8*)&qkv[qr * 3072 + hq + 32 + fk];
  }

  const int kr0 = tid >> 3, kr1 = 32 + (tid >> 3);
  const unsigned short* Kg0 = &qkv[(rowbase + kr0) * 3072 + 1024 + hq + (((tid & 7) ^ (kr0 & 7)) * 8)];
  const unsigned short* Kg1 = &qkv[(rowbase + kr1) * 3072 + 1024 + hq + (((tid & 7) ^ (kr1 & 7)) * 8)];
  const int vkv0 = ((tid >> 3) & 3) * 8 + ((tid >> 5) & 1) * 4 + ((tid >> 1) & 3);
  const int vd0 = ((tid >> 6) & 3) * 16 + (tid & 1) * 8;
  const unsigned short* Vg0 = &qkv[(rowbase + vkv0) * 3072 + 2048 + hq + vd0];
  const unsigned short* Vg1 = &qkv[(rowbase + vkv0 + 32) * 3072 + 2048 + hq + vd0];

  auto stage = [&](int buf) {
    gload_lds16(Kg0, &Ks[buf * 4096 + tid * 8]);
    gload_lds16(Kg1, &Ks[buf * 4096 + 2048 + tid * 8]);
    gload_lds16(Vg0, &Vs[buf * 4096 + tid * 8]);
    gload_lds16(Vg1, &Vs[buf * 4096 + 2048 + tid * 8]);
    Kg0 += 64 * 3072; Kg1 += 64 * 3072; Vg0 += 64 * 3072; Vg1 += 64 * 3072;
  };

  short8 onesv;
#pragma unroll
  for (int e = 0; e < 8; e++) onesv[e] = (short)0x3F80;  // bf16 1.0

  f32x4 o[4] = {};
  f32x4 s_acc = {0.f, 0.f, 0.f, 0.f};
  float m_[4];
#pragma unroll
  for (int r = 0; r < 4; r++) m_[r] = -1e30f;

  stage(0);
  __syncthreads();

  for (int t = 0; t < 32; t++) {
    const int cur = t & 1;
    if (t < 31) stage(cur ^ 1);

    short8 kf[4][2];
#pragma unroll
    for (int n = 0; n < 4; n++) {
      const int row = n * 16 + fr;
#pragma unroll
      for (int kc = 0; kc < 2; kc++) {
        const int idx = (row * 64 + kc * 32 + fk) ^ ((row & 7) << 3);
        kf[n][kc] = *(const short8*)&Ks[cur * 4096 + idx];
      }
    }
    f32x4 sa[4];
    __builtin_amdgcn_s_setprio(1);
#pragma unroll
    for (int n = 0; n < 4; n++) {
      f32x4 z = {0.f, 0.f, 0.f, 0.f};
      z = __builtin_amdgcn_mfma_f32_16x16x32_bf16(qf[0], kf[n][0], z, 0, 0, 0);
      sa[n] = __builtin_amdgcn_mfma_f32_16x16x32_bf16(qf[1], kf[n][1], z, 0, 0, 0);
    }
    __builtin_amdgcn_s_setprio(0);

    float lmax;
    {
      float a0 = fmaxf(fmaxf(sa[0][0], sa[0][1]), fmaxf(sa[0][2], sa[0][3]));
      float a1 = fmaxf(fmaxf(sa[1][0], sa[1][1]), fmaxf(sa[1][2], sa[1][3]));
      float a2 = fmaxf(fmaxf(sa[2][0], sa[2][1]), fmaxf(sa[2][2], sa[2][3]));
      float a3 = fmaxf(fmaxf(sa[3][0], sa[3][1]), fmaxf(sa[3][2], sa[3][3]));
      lmax = fmaxf(fmaxf(a0, a1), fmaxf(a2, a3));
    }
    const float mmin = fminf(fminf(m_[0], m_[1]), fminf(m_[2], m_[3]));
    if (__any(lmax - mmin > 8.f)) {
      float mx[4];
#pragma unroll
      for (int r = 0; r < 4; r++)
        mx[r] = fmaxf(fmaxf(sa[0][r], sa[1][r]), fmaxf(sa[2][r], sa[3][r]));
#pragma unroll
      for (int r = 0; r < 4; r++) {
        for (int off = 1; off < 16; off <<= 1) mx[r] = fmaxf(mx[r], __shfl_xor(mx[r], off));
      }
#pragma unroll
      for (int r = 0; r < 4; r++) {
        const float nm = fmaxf(m_[r], mx[r]);
        const float fac = __builtin_amdgcn_exp2f(m_[r] - nm);
        m_[r] = nm;
        s_acc[r] *= fac;
#pragma unroll
        for (int dj = 0; dj < 4; dj++) o[dj][r] *= fac;
      }
    }

#pragma unroll
    for (int n = 0; n < 4; n++)
#pragma unroll
      for (int r = 0; r < 4; r++) {
        const float p = __builtin_amdgcn_exp2f(sa[n][r] - m_[r]);
        const int row = w * 16 + fg * 4 + r;
        const int col = (n * 16 + fr) ^ (((fg * 4 + r) & 7) << 3);
        Ps[row * 64 + col] = f2bf_trunc(p);
      }

    short8 pa[2];
#pragma unroll
    for (int kc = 0; kc < 2; kc++)
      pa[kc] = *(const short8*)&Ps[(w * 16 + fr) * 64 + ((kc * 32 + fk) ^ ((fr & 7) << 3))];

    s_acc = __builtin_amdgcn_mfma_f32_16x16x32_bf16(pa[0], onesv, s_acc, 0, 0, 0);
    s_acc = __builtin_amdgcn_mfma_f32_16x16x32_bf16(pa[1], onesv, s_acc, 0, 0, 0);

    // tr-reads issued dj-major; counted lgkm waits interleave reads with PV MFMA
    const __attribute__((address_space(3))) unsigned short* vtr =
        (const __attribute__((address_space(3))) unsigned short*)&Vs[0] + cur * 4096 + lane * 4;
    short4v v0[4][2], v1[4][2];
    TRRD(v0[0][0], "0");    TRRD(v1[0][0], "512");  TRRD(v0[0][1], "4096"); TRRD(v1[0][1], "4608");
    TRRD(v0[1][0], "1024"); TRRD(v1[1][0], "1536"); TRRD(v0[1][1], "5120"); TRRD(v1[1][1], "5632");
    TRRD(v0[2][0], "2048"); TRRD(v1[2][0], "2560"); TRRD(v0[2][1], "6144"); TRRD(v1[2][1], "6656");
    TRRD(v0[3][0], "3072"); TRRD(v1[3][0], "3584"); TRRD(v0[3][1], "7168"); TRRD(v1[3][1], "7680");

    __builtin_amdgcn_s_setprio(1);
    LGKM(12); __builtin_amdgcn_sched_barrier(0);
#pragma unroll
    for (int kc = 0; kc < 2; kc++) {
      short8 vf = __builtin_shufflevector(v0[0][kc], v1[0][kc], 0, 1, 2, 3, 4, 5, 6, 7);
      o[0] = __builtin_amdgcn_mfma_f32_16x16x32_bf16(pa[kc], vf, o[0], 0, 0, 0);
    }
    LGKM(8); __builtin_amdgcn_sched_barrier(0);
#pragma unroll
    for (int kc = 0; kc < 2; kc++) {
      short8 vf = __builtin_shufflevector(v0[1][kc], v1[1][kc], 0, 1, 2, 3, 4, 5, 6, 7);
      o[1] = __builtin_amdgcn_mfma_f32_16x16x32_bf16(pa[kc], vf, o[1], 0, 0, 0);
    }
    LGKM(4); __builtin_amdgcn_sched_barrier(0);
#pragma unroll
    for (int kc = 0; kc < 2; kc++) {
      short8 vf = __builtin_shufflevector(v0[2][kc], v1[2][kc], 0, 1, 2, 3, 4, 5, 6, 7);
      o[2] = __builtin_amdgcn_mfma_f32_16x16x32_bf16(pa[kc], vf, o[2], 0, 0, 0);
    }
    LGKM(0); __builtin_amdgcn_sched_barrier(0);
#pragma unroll
    for (int kc = 0; kc < 2; kc++) {
      short8 vf = __builtin_shufflevector(v0[3][kc], v1[3][kc], 0, 1, 2, 3, 4, 5, 6, 7);
      o[3] = __builtin_amdgcn_mfma_f32_16x16x32_bf16(pa[kc], vf, o[3], 0, 0, 0);
    }
    __builtin_amdgcn_s_setprio(0);
    __syncthreads();
  }

  float rs[4];
#pragma unroll
  for (int r = 0; r < 4; r++) rs[r] = __builtin_amdgcn_rcpf(s_acc[r]);
#pragma unroll
  for (int dj = 0; dj < 4; dj++)
#pragma unroll
    for (int r = 0; r < 4; r++) {
      const long row = rowbase + q0 + fg * 4 + r;
      out[row * 1024 + hq + dj * 16 + fr] = f2bf(o[dj][r] * rs[r]);
    }
}

// ---------------- host ----------------

extern "C" void kernel_launch(void* const* d_in, const int* in_sizes, int n_in,
                              void* d_out, int out_size, void* d_ws, size_t ws_size,
                              hipStream_t stream) {
  const float* x  = (const float*)d_in[0];
  const float* wq = (const float*)d_in[1];
  const float* bq = (const float*)d_in[2];
  const float* wk = (const float*)d_in[3];
  const float* bk = (const float*)d_in[4];
  const float* wv = (const float*)d_in[5];
  const float* bv = (const float*)d_in[6];
  const float* wo = (const float*)d_in[7];
  const float* bo = (const float*)d_in[8];

  char* ws = (char*)d_ws;
  unsigned short* xb    = (unsigned short*)(ws);                       // 8 MB  [4096][1024]
  unsigned short* wqkvT = (unsigned short*)(ws + (8ull  << 20));       // 6 MB  [3072][1024]
  unsigned short* woT   = (unsigned short*)(ws + (14ull << 20));       // 2 MB  [1024][1024]
  float*          bqkv  = (float*)         (ws + (16ull << 20));       // 12 KB [3072]
  unsigned short* qkv   = (unsigned short*)(ws + (17ull << 20));       // 24 MB [4096][3072]
  unsigned short* attn  = (unsigned short*)(ws + (41ull << 20));       // 8 MB  [4096][1024]

  cvt_bf16<<<4096, 256, 0, stream>>>((const float4*)x, (ushort4*)xb);
  cvt_wT_all<<<dim3(32, 32, 4), 256, 0, stream>>>(wq, wk, wv, wo, wqkvT, woT);
  pack_bias<<<12, 256, 0, stream>>>(bq, bk, bv, bqkv);

  // QKV projection: [4096,1024] @ [1024,3072] via 256^2 8-phase kernel
  gemm256<<<dim3(16, 12), 512, 0, stream>>>(xb, wqkvT, bqkv, qkv, 3072);

  attn_fwd<<<1024, 256, 0, stream>>>(qkv, attn);

  gemm_bt<float><<<dim3(32, 8), 256, 0, stream>>>(attn, woT, bo, (float*)d_out, 1024, 1024);
}

// Round 7
// 135.011 us; speedup vs baseline: 1.6250x; 1.0091x over previous
//
#include <hip/hip_runtime.h>

typedef __attribute__((ext_vector_type(8))) short short8;
typedef __attribute__((ext_vector_type(4))) short short4v;
typedef __attribute__((ext_vector_type(8))) unsigned short u16x8;
typedef __attribute__((ext_vector_type(4))) float f32x4;

__device__ inline unsigned short f2bf(float f) {
  union { float f; unsigned int u; } v; v.f = f;
  unsigned int r = v.u + 0x7FFFu + ((v.u >> 16) & 1u);
  return (unsigned short)(r >> 16);
}

__device__ inline unsigned short f2bf_trunc(float f) {
  union { float f; unsigned int u; } v; v.f = f;
  return (unsigned short)(v.u >> 16);
}

__device__ inline void gload_lds16(const void* g, void* l) {
  __builtin_amdgcn_global_load_lds(
      (const __attribute__((address_space(1))) unsigned int*)g,
      (__attribute__((address_space(3))) unsigned int*)l, 16, 0, 0);
}

// ---------------- conversion kernels ----------------

__global__ void cvt_bf16(const float4* __restrict__ in, ushort4* __restrict__ out) {
  const int i = blockIdx.x * blockDim.x + threadIdx.x;
  float4 v = in[i];
  ushort4 o;
  o.x = f2bf(v.x); o.y = f2bf(v.y); o.z = f2bf(v.z); o.w = f2bf(v.w);
  out[i] = o;
}

// all four weight transposes in one launch (z = 0..3 -> wq,wk,wv,wo)
__global__ __launch_bounds__(256) void cvt_wT_all(
    const float* __restrict__ wq, const float* __restrict__ wk,
    const float* __restrict__ wv, const float* __restrict__ wo,
    unsigned short* __restrict__ wqkvT, unsigned short* __restrict__ woT) {
  const int z = blockIdx.z;
  const float* w = (z == 0) ? wq : (z == 1) ? wk : (z == 2) ? wv : wo;
  unsigned short* dst = (z < 3) ? (wqkvT + (size_t)z * 1024 * 1024) : woT;
  const float scale = (z == 0) ? 0.18033688011f : 1.0f;  // 0.125*log2(e) on Q path
  __shared__ float t[32][33];
  const int k0 = blockIdx.x * 32;
  const int n0 = blockIdx.y * 32;
  const int tx = threadIdx.x & 31, ty = threadIdx.x >> 5;  // 32 x 8
#pragma unroll
  for (int i = 0; i < 32; i += 8)
    t[ty + i][tx] = w[(size_t)(k0 + ty + i) * 1024 + n0 + tx];
  __syncthreads();
#pragma unroll
  for (int i = 0; i < 32; i += 8)
    dst[(size_t)(n0 + ty + i) * 1024 + k0 + tx] = f2bf(t[tx][ty + i] * scale);
}

__global__ void pack_bias(const float* __restrict__ bq, const float* __restrict__ bk,
                          const float* __restrict__ bv, float* __restrict__ out) {
  const int i = blockIdx.x * 256 + threadIdx.x;  // 0..3071
  float v;
  if (i < 1024) v = bq[i] * 0.18033688011f;
  else if (i < 2048) v = bk[i - 1024];
  else v = bv[i - 2048];
  out[i] = v;
}

// ---------------- GEMM 128^2 (m97 structure) — used for O-projection ----------------

template <typename OutT>
__global__ __launch_bounds__(256) void gemm_bt(
    const unsigned short* __restrict__ A, const unsigned short* __restrict__ Bt,
    const float* __restrict__ bias, OutT* __restrict__ C,
    int K, int ldc) {
  __shared__ unsigned short As[128 * 32];
  __shared__ unsigned short Bs[128 * 32];
  const int tid = threadIdx.x;
  const int lane = tid & 63;
  const int wave = tid >> 6;
  const int wm = (wave >> 1) * 64;
  const int wn = (wave & 1) * 64;
  const long bm = (long)blockIdx.x * 128;
  const long bn = (long)blockIdx.y * 128;

  const int sr = tid >> 2;
  const int sc = (tid & 3) * 8;
  const unsigned short* Ag0 = A + (bm + sr) * (long)K + sc;
  const unsigned short* Ag1 = A + (bm + 64 + sr) * (long)K + sc;
  const unsigned short* Bg0 = Bt + (bn + sr) * (long)K + sc;
  const unsigned short* Bg1 = Bt + (bn + 64 + sr) * (long)K + sc;
  unsigned short* As0 = &As[tid * 8];
  unsigned short* As1 = &As[2048 + tid * 8];
  unsigned short* Bs0 = &Bs[tid * 8];
  unsigned short* Bs1 = &Bs[2048 + tid * 8];

  f32x4 acc[4][4] = {};

  const int fr = lane & 15;
  const int fk = (lane >> 4) * 8;

  for (int kt = 0; kt < K; kt += 32) {
    gload_lds16(Ag0, As0);
    gload_lds16(Ag1, As1);
    gload_lds16(Bg0, Bs0);
    gload_lds16(Bg1, Bs1);
    Ag0 += 32; Ag1 += 32; Bg0 += 32; Bg1 += 32;
    __syncthreads();
    short8 af[4], bfv[4];
#pragma unroll
    for (int i = 0; i < 4; i++) af[i] = *(const short8*)&As[(wm + i * 16 + fr) * 32 + fk];
#pragma unroll
    for (int j = 0; j < 4; j++) bfv[j] = *(const short8*)&Bs[(wn + j * 16 + fr) * 32 + fk];
#pragma unroll
    for (int i = 0; i < 4; i++)
#pragma unroll
      for (int j = 0; j < 4; j++)
        acc[i][j] = __builtin_amdgcn_mfma_f32_16x16x32_bf16(af[i], bfv[j], acc[i][j], 0, 0, 0);
    __syncthreads();
  }

  const int crow = (lane >> 4) * 4;
  const int ccol = lane & 15;
#pragma unroll
  for (int j = 0; j < 4; j++) {
    const long col = bn + wn + j * 16 + ccol;
    const float bv = bias[col];
#pragma unroll
    for (int i = 0; i < 4; i++) {
#pragma unroll
      for (int r = 0; r < 4; r++) {
        const long row = bm + wm + i * 16 + crow + r;
        const float val = acc[i][j][r] + bv;
        if constexpr (__is_same(OutT, float)) C[row * ldc + col] = val;
        else                                  C[row * ldc + col] = f2bf(val);
      }
    }
  }
}

// ---------------- GEMM 256^2, BK=64, 8 waves, 8-phase counted-vmcnt ----------------

__global__ __launch_bounds__(512, 2) void gemm256(
    const unsigned short* __restrict__ A, const unsigned short* __restrict__ Bt,
    const float* __restrict__ bias, unsigned short* __restrict__ C, int ldc) {
  constexpr int K = 1024;
  __shared__ unsigned short Sab[2][2][16384];  // [buf][0=A,1=B][256*64]
  const int tid = threadIdx.x;
  const int lane = tid & 63;
  const int w = tid >> 6;
  const int wr = w >> 2, wc = w & 3;
  const long bm = (long)blockIdx.x * 256;
  const long bn = (long)blockIdx.y * 256;
  const int fr = lane & 15, fg = lane >> 4;

  const int srow = tid >> 3;  // 0..63
  const int kch = tid & 7;

  auto stage = [&](int o, int buf, int tk, int h) {
#pragma unroll
    for (int l = 0; l < 2; ++l) {
      const int rih = l * 64 + srow;  // row in half 0..127
      const unsigned short* src = (o ? Bt : A) +
          ((o ? bn : bm) + h * 128 + rih) * (long)K + tk * 64 + ((kch ^ (rih & 7)) * 8);
      gload_lds16(src, &Sab[buf][o][h * 8192 + (l * 512 + tid) * 8]);
    }
  };

  f32x4 acc[8][4] = {};

  stage(0, 0, 0, 0); stage(0, 0, 0, 1);
  stage(1, 0, 0, 0); stage(1, 0, 0, 1);
  stage(1, 1, 1, 0); stage(1, 1, 1, 1);
  asm volatile("s_waitcnt vmcnt(4)" ::: "memory");
  __builtin_amdgcn_s_barrier();

  for (int it = 0; it < 8; ++it) {
    const int T = 2 * it;
    const int tkA = (T + 2 < 15) ? T + 2 : 15;
    const int tkB3 = (T + 3 < 15) ? T + 3 : 15;
#pragma unroll
    for (int half = 0; half < 2; ++half) {
      const int b = half;
      short8 bfr[4][2];
      short8 afr[2][2];
#pragma unroll
      for (int g = 0; g < 4; ++g) {
        if (g == 0) {
#pragma unroll
          for (int nj = 0; nj < 4; ++nj)
#pragma unroll
            for (int kc = 0; kc < 2; ++kc) {
              const int r = wc * 64 + nj * 16 + fr;
              bfr[nj][kc] = *(const short8*)&Sab[b][1][r * 64 + ((kc * 4 + fg) ^ (r & 7)) * 8];
            }
        }
#pragma unroll
        for (int mil = 0; mil < 2; ++mil)
#pragma unroll
          for (int kc = 0; kc < 2; ++kc) {
            const int r = wr * 128 + (2 * g + mil) * 16 + fr;
            afr[mil][kc] = *(const short8*)&Sab[b][0][r * 64 + ((kc * 4 + fg) ^ (r & 7)) * 8];
          }
        if (half == 0) {
          if (g == 0)      { stage(0, 1, T + 1, 0); stage(0, 1, T + 1, 1); }
          else if (g == 1) { stage(1, 0, tkA, 0); }
          else if (g == 2) { stage(1, 0, tkA, 1); }
        } else {
          if (g == 0)      { stage(0, 0, tkA, 0); stage(0, 0, tkA, 1); }
          else if (g == 1) { stage(1, 1, tkB3, 0); }
          else if (g == 2) { stage(1, 1, tkB3, 1); }
        }
        __builtin_amdgcn_s_barrier();
        asm volatile("s_waitcnt lgkmcnt(0)" ::: "memory");
        __builtin_amdgcn_sched_barrier(0);
        __builtin_amdgcn_s_setprio(1);
#pragma unroll
        for (int mil = 0; mil < 2; ++mil)
#pragma unroll
          for (int nj = 0; nj < 4; ++nj)
#pragma unroll
            for (int kc = 0; kc < 2; ++kc)
              acc[2 * g + mil][nj] = __builtin_amdgcn_mfma_f32_16x16x32_bf16(
                  afr[mil][kc], bfr[nj][kc], acc[2 * g + mil][nj], 0, 0, 0);
        __builtin_amdgcn_s_setprio(0);
        if (g == 3) asm volatile("s_waitcnt vmcnt(4)" ::: "memory");
        __builtin_amdgcn_s_barrier();
      }
    }
  }

  const int crow = fg * 4;
  const int ccol = fr;
#pragma unroll
  for (int nj = 0; nj < 4; ++nj) {
    const long col = bn + wc * 64 + nj * 16 + ccol;
    const float bv = bias[col];
#pragma unroll
    for (int mi = 0; mi < 8; ++mi)
#pragma unroll
      for (int r = 0; r < 4; ++r) {
        const long row = bm + wr * 128 + mi * 16 + crow + r;
        C[row * ldc + col] = f2bf(acc[mi][nj][r] + bv);
      }
  }
}

// ---------------- flash attention (v6: 2x2 q-half x kv-half wave split) ----------------
// Each wave owns (q 32 rows) x (kv half 32 rows) of each KV tile -> per-wave LDS
// traffic drops 20KB->12KB per tile (kf 8->4, tr 16->8) — the round-6 LDS-pipe bound.
// Independent online softmax per wave; LSE merge across kv-halves at the end
// (kh=1 waves dump (m,s,o) to retired Ks/Vs regions, kh=0 waves merge + write).

#define TRRD(d, o) asm volatile("ds_read_b64_tr_b16 %0, %1 offset:" o \
                                : "=v"(d) : "v"(vtr) : "memory")
#define LGKM(n) asm volatile("s_waitcnt lgkmcnt(" #n ")" ::: "memory")

__global__ __launch_bounds__(256, 4) void attn_fwd(
    const unsigned short* __restrict__ qkv, unsigned short* __restrict__ out) {
  __shared__ unsigned short Ks[2 * 4096];
  __shared__ unsigned short Vs[2 * 4096];
  __shared__ unsigned short Ps[64 * 64];
  const int tid = threadIdx.x;
  const int lane = tid & 63;
  const int w = tid >> 6;
  const int qh = w >> 1, kh = w & 1;

  const int xcd = blockIdx.x & 7, slot = blockIdx.x >> 3;
  const int pair = xcd * 4 + (slot >> 5);
  const int qtile = slot & 31;
  const int h = pair & 15, b = pair >> 4;
  const long rowbase = (long)b * 2048;
  const int hq = h * 64;
  const int fr = lane & 15;
  const int fg = lane >> 4;
  const int fk = fg * 8;
  const int q0 = qtile * 64 + qh * 32;

  // Q fragments: 2 q-tiles (rows q0+qi*16+fr), pre-scaled by 0.125*log2e
  short8 qf[2][2];
#pragma unroll
  for (int qi = 0; qi < 2; qi++) {
    const long qr = rowbase + q0 + qi * 16 + fr;
    qf[qi][0] = *(const short8*)&qkv[qr * 3072 + hq + fk];
    qf[qi][1] = *(const short8*)&qkv[qr * 3072 + hq + 32 + fk];
  }

  // staging (block-wide, unchanged layout)
  const int kr0 = tid >> 3, kr1 = 32 + (tid >> 3);
  const unsigned short* Kg0 = &qkv[(rowbase + kr0) * 3072 + 1024 + hq + (((tid & 7) ^ (kr0 & 7)) * 8)];
  const unsigned short* Kg1 = &qkv[(rowbase + kr1) * 3072 + 1024 + hq + (((tid & 7) ^ (kr1 & 7)) * 8)];
  const int vkv0 = ((tid >> 3) & 3) * 8 + ((tid >> 5) & 1) * 4 + ((tid >> 1) & 3);
  const int vd0 = ((tid >> 6) & 3) * 16 + (tid & 1) * 8;
  const unsigned short* Vg0 = &qkv[(rowbase + vkv0) * 3072 + 2048 + hq + vd0];
  const unsigned short* Vg1 = &qkv[(rowbase + vkv0 + 32) * 3072 + 2048 + hq + vd0];

  auto stage = [&](int buf) {
    gload_lds16(Kg0, &Ks[buf * 4096 + tid * 8]);
    gload_lds16(Kg1, &Ks[buf * 4096 + 2048 + tid * 8]);
    gload_lds16(Vg0, &Vs[buf * 4096 + tid * 8]);
    gload_lds16(Vg1, &Vs[buf * 4096 + 2048 + tid * 8]);
    Kg0 += 64 * 3072; Kg1 += 64 * 3072; Vg0 += 64 * 3072; Vg1 += 64 * 3072;
  };

  short8 onesv;
#pragma unroll
  for (int e = 0; e < 8; e++) onesv[e] = (short)0x3F80;  // bf16 1.0

  f32x4 o[2][4] = {};
  f32x4 s_acc[2] = {};
  float m_[2][4];
#pragma unroll
  for (int qi = 0; qi < 2; qi++)
#pragma unroll
    for (int r = 0; r < 4; r++) m_[qi][r] = -1e30f;

  stage(0);
  __syncthreads();

  for (int t = 0; t < 32; t++) {
    const int cur = t & 1;
    if (t < 31) stage(cur ^ 1);

    // QK^T: wave's kv half only (rows kh*32 + n*16 + fr), both d halves
    f32x4 sa[2][2];
    __builtin_amdgcn_s_setprio(1);
#pragma unroll
    for (int n = 0; n < 2; n++) {
      const int row = kh * 32 + n * 16 + fr;
      const short8 kf0 = *(const short8*)&Ks[cur * 4096 + ((row * 64 + fk) ^ ((fr & 7) << 3))];
      const short8 kf1 = *(const short8*)&Ks[cur * 4096 + ((row * 64 + 32 + fk) ^ ((fr & 7) << 3))];
#pragma unroll
      for (int qi = 0; qi < 2; qi++) {
        f32x4 z = {0.f, 0.f, 0.f, 0.f};
        z = __builtin_amdgcn_mfma_f32_16x16x32_bf16(qf[qi][0], kf0, z, 0, 0, 0);
        sa[qi][n] = __builtin_amdgcn_mfma_f32_16x16x32_bf16(qf[qi][1], kf1, z, 0, 0, 0);
      }
    }
    __builtin_amdgcn_s_setprio(0);

    // defer-max gate (per-wave): P <= 2^8 guaranteed by lmax - mmin <= 8
    float lmax;
    {
      float a0 = fmaxf(fmaxf(sa[0][0][0], sa[0][0][1]), fmaxf(sa[0][0][2], sa[0][0][3]));
      float a1 = fmaxf(fmaxf(sa[0][1][0], sa[0][1][1]), fmaxf(sa[0][1][2], sa[0][1][3]));
      float a2 = fmaxf(fmaxf(sa[1][0][0], sa[1][0][1]), fmaxf(sa[1][0][2], sa[1][0][3]));
      float a3 = fmaxf(fmaxf(sa[1][1][0], sa[1][1][1]), fmaxf(sa[1][1][2], sa[1][1][3]));
      lmax = fmaxf(fmaxf(a0, a1), fmaxf(a2, a3));
    }
    float mmin = m_[0][0];
#pragma unroll
    for (int qi = 0; qi < 2; qi++)
#pragma unroll
      for (int r = 0; r < 4; r++) mmin = fminf(mmin, m_[qi][r]);
    if (__any(lmax - mmin > 8.f)) {
#pragma unroll
      for (int qi = 0; qi < 2; qi++) {
        float mx[4];
#pragma unroll
        for (int r = 0; r < 4; r++) mx[r] = fmaxf(sa[qi][0][r], sa[qi][1][r]);
#pragma unroll
        for (int r = 0; r < 4; r++) {
          for (int off = 1; off < 16; off <<= 1) mx[r] = fmaxf(mx[r], __shfl_xor(mx[r], off));
        }
#pragma unroll
        for (int r = 0; r < 4; r++) {
          const float nm = fmaxf(m_[qi][r], mx[r]);
          const float fac = __builtin_amdgcn_exp2f(m_[qi][r] - nm);
          m_[qi][r] = nm;
          s_acc[qi][r] *= fac;
#pragma unroll
          for (int dj = 0; dj < 4; dj++) o[qi][dj][r] *= fac;
        }
      }
    }

    // P = exp2(sa - m) -> swizzled Ps quadrant (rows qh*32.., orig cols kh*32..)
#pragma unroll
    for (int qi = 0; qi < 2; qi++)
#pragma unroll
      for (int n = 0; n < 2; n++)
#pragma unroll
        for (int r = 0; r < 4; r++) {
          const float p = __builtin_amdgcn_exp2f(sa[qi][n][r] - m_[qi][r]);
          const int prow = qh * 32 + qi * 16 + fg * 4 + r;
          const int pcol = (kh * 32 + n * 16 + fr) ^ ((prow & 7) << 3);
          Ps[prow * 64 + pcol] = f2bf_trunc(p);
        }

    // P A-fragments (wave-private quadrant)
    short8 pa[2];
#pragma unroll
    for (int qi = 0; qi < 2; qi++) {
      const int rrow = qh * 32 + qi * 16 + fr;
      pa[qi] = *(const short8*)&Ps[rrow * 64 + (((kh * 4 + fg) ^ (fr & 7)) * 8)];
    }

    s_acc[0] = __builtin_amdgcn_mfma_f32_16x16x32_bf16(pa[0], onesv, s_acc[0], 0, 0, 0);
    s_acc[1] = __builtin_amdgcn_mfma_f32_16x16x32_bf16(pa[1], onesv, s_acc[1], 0, 0, 0);

    // V^T fragments: only this wave's kv half (kh folded into base)
    const __attribute__((address_space(3))) unsigned short* vtr =
        (const __attribute__((address_space(3))) unsigned short*)&Vs[0] +
        cur * 4096 + kh * 2048 + lane * 4;
    short4v v0[4], v1[4];
    TRRD(v0[0], "0");    TRRD(v1[0], "512");
    TRRD(v0[1], "1024"); TRRD(v1[1], "1536");
    TRRD(v0[2], "2048"); TRRD(v1[2], "2560");
    TRRD(v0[3], "3072"); TRRD(v1[3], "3584");

    __builtin_amdgcn_s_setprio(1);
    LGKM(6); __builtin_amdgcn_sched_barrier(0);
    {
      short8 vf = __builtin_shufflevector(v0[0], v1[0], 0, 1, 2, 3, 4, 5, 6, 7);
      o[0][0] = __builtin_amdgcn_mfma_f32_16x16x32_bf16(pa[0], vf, o[0][0], 0, 0, 0);
      o[1][0] = __builtin_amdgcn_mfma_f32_16x16x32_bf16(pa[1], vf, o[1][0], 0, 0, 0);
    }
    LGKM(4); __builtin_amdgcn_sched_barrier(0);
    {
      short8 vf = __builtin_shufflevector(v0[1], v1[1], 0, 1, 2, 3, 4, 5, 6, 7);
      o[0][1] = __builtin_amdgcn_mfma_f32_16x16x32_bf16(pa[0], vf, o[0][1], 0, 0, 0);
      o[1][1] = __builtin_amdgcn_mfma_f32_16x16x32_bf16(pa[1], vf, o[1][1], 0, 0, 0);
    }
    LGKM(2); __builtin_amdgcn_sched_barrier(0);
    {
      short8 vf = __builtin_shufflevector(v0[2], v1[2], 0, 1, 2, 3, 4, 5, 6, 7);
      o[0][2] = __builtin_amdgcn_mfma_f32_16x16x32_bf16(pa[0], vf, o[0][2], 0, 0, 0);
      o[1][2] = __builtin_amdgcn_mfma_f32_16x16x32_bf16(pa[1], vf, o[1][2], 0, 0, 0);
    }
    LGKM(0); __builtin_amdgcn_sched_barrier(0);
    {
      short8 vf = __builtin_shufflevector(v0[3], v1[3], 0, 1, 2, 3, 4, 5, 6, 7);
      o[0][3] = __builtin_amdgcn_mfma_f32_16x16x32_bf16(pa[0], vf, o[0][3], 0, 0, 0);
      o[1][3] = __builtin_amdgcn_mfma_f32_16x16x32_bf16(pa[1], vf, o[1][3], 0, 0, 0);
    }
    __builtin_amdgcn_s_setprio(0);
    __syncthreads();
  }

  // -------- kv-half LSE merge (Ks/Vs regions are retired after final barrier) --------
  float* mo = (float*)&Ks[0];  // 4096 f32: [wqh][i 0..31][lane]
  float* ms = (float*)&Vs[0];  // 2048 f32: [wqh][i 0..15][lane]
  if (kh == 1) {
#pragma unroll
    for (int qi = 0; qi < 2; qi++)
#pragma unroll
      for (int dj = 0; dj < 4; dj++)
#pragma unroll
        for (int r = 0; r < 4; r++)
          mo[qh * 2048 + (qi * 16 + dj * 4 + r) * 64 + lane] = o[qi][dj][r];
#pragma unroll
    for (int qi = 0; qi < 2; qi++)
#pragma unroll
      for (int r = 0; r < 4; r++) {
        ms[qh * 1024 + (qi * 4 + r) * 64 + lane] = m_[qi][r];
        ms[qh * 1024 + (8 + qi * 4 + r) * 64 + lane] = s_acc[qi][r];
      }
  }
  __syncthreads();
  if (kh == 0) {
    float f0[2][4], f1[2][4], rs[2][4];
#pragma unroll
    for (int qi = 0; qi < 2; qi++)
#pragma unroll
      for (int r = 0; r < 4; r++) {
        const float m1 = ms[qh * 1024 + (qi * 4 + r) * 64 + lane];
        const float s1 = ms[qh * 1024 + (8 + qi * 4 + r) * 64 + lane];
        const float m0 = m_[qi][r], s0 = s_acc[qi][r];
        const float mstar = fmaxf(m0, m1);
        f0[qi][r] = __builtin_amdgcn_exp2f(m0 - mstar);
        f1[qi][r] = __builtin_amdgcn_exp2f(m1 - mstar);
        rs[qi][r] = __builtin_amdgcn_rcpf(s0 * f0[qi][r] + s1 * f1[qi][r]);
      }
#pragma unroll
    for (int qi = 0; qi < 2; qi++)
#pragma unroll
      for (int dj = 0; dj < 4; dj++)
#pragma unroll
        for (int r = 0; r < 4; r++) {
          const float o1 = mo[qh * 2048 + (qi * 16 + dj * 4 + r) * 64 + lane];
          const float val = (o[qi][dj][r] * f0[qi][r] + o1 * f1[qi][r]) * rs[qi][r];
          const long row = rowbase + q0 + qi * 16 + fg * 4 + r;
          out[row * 1024 + hq + dj * 16 + fr] = f2bf(val);
        }
  }
}

// ---------------- host ----------------

extern "C" void kernel_launch(void* const* d_in, const int* in_sizes, int n_in,
                              void* d_out, int out_size, void* d_ws, size_t ws_size,
                              hipStream_t stream) {
  const float* x  = (const float*)d_in[0];
  const float* wq = (const float*)d_in[1];
  const float* bq = (const float*)d_in[2];
  const float* wk = (const float*)d_in[3];
  const float* bk = (const float*)d_in[4];
  const float* wv = (const float*)d_in[5];
  const float* bv = (const float*)d_in[6];
  const float* wo = (const float*)d_in[7];
  const float* bo = (const float*)d_in[8];

  char* ws = (char*)d_ws;
  unsigned short* xb    = (unsigned short*)(ws);                       // 8 MB  [4096][1024]
  unsigned short* wqkvT = (unsigned short*)(ws + (8ull  << 20));       // 6 MB  [3072][1024]
  unsigned short* woT   = (unsigned short*)(ws + (14ull << 20));       // 2 MB  [1024][1024]
  float*          bqkv  = (float*)         (ws + (16ull << 20));       // 12 KB [3072]
  unsigned short* qkv   = (unsigned short*)(ws + (17ull << 20));       // 24 MB [4096][3072]
  unsigned short* attn  = (unsigned short*)(ws + (41ull << 20));       // 8 MB  [4096][1024]

  cvt_bf16<<<4096, 256, 0, stream>>>((const float4*)x, (ushort4*)xb);
  cvt_wT_all<<<dim3(32, 32, 4), 256, 0, stream>>>(wq, wk, wv, wo, wqkvT, woT);
  pack_bias<<<12, 256, 0, stream>>>(bq, bk, bv, bqkv);

  gemm256<<<dim3(16, 12), 512, 0, stream>>>(xb, wqkvT, bqkv, qkv, 3072);

  attn_fwd<<<1024, 256, 0, stream>>>(qkv, attn);

  gemm_bt<float><<<dim3(32, 8), 256, 0, stream>>>(attn, woT, bo, (float*)d_out, 1024, 1024);
}

// Round 8
// 127.607 us; speedup vs baseline: 1.7193x; 1.0580x over previous
//
#include <hip/hip_runtime.h>

typedef __attribute__((ext_vector_type(8))) short short8;
typedef __attribute__((ext_vector_type(4))) short short4v;
typedef __attribute__((ext_vector_type(4))) float f32x4;

__device__ inline unsigned short f2bf(float f) {
  union { float f; unsigned int u; } v; v.f = f;
  unsigned int r = v.u + 0x7FFFu + ((v.u >> 16) & 1u);
  return (unsigned short)(r >> 16);
}

__device__ inline unsigned cvtpk_bf16(float lo, float hi) {
  unsigned r;
  asm("v_cvt_pk_bf16_f32 %0, %1, %2" : "=v"(r) : "v"(lo), "v"(hi));
  return r;
}

__device__ inline void gload_lds16(const void* g, void* l) {
  __builtin_amdgcn_global_load_lds(
      (const __attribute__((address_space(1))) unsigned int*)g,
      (__attribute__((address_space(3))) unsigned int*)l, 16, 0, 0);
}

// ---------------- fused prep: x->bf16 | 4x weight transpose | bias pack ----------------

__global__ __launch_bounds__(256) void prep(
    const float* __restrict__ x,
    const float* __restrict__ wq, const float* __restrict__ wk,
    const float* __restrict__ wv, const float* __restrict__ wo,
    const float* __restrict__ bq, const float* __restrict__ bk,
    const float* __restrict__ bv,
    unsigned short* __restrict__ xb, unsigned short* __restrict__ wqkvT,
    unsigned short* __restrict__ woT, float* __restrict__ bqkv) {
  const int bid = blockIdx.x;
  if (bid < 4096) {  // x -> bf16 (float4/ushort4 per thread)
    const int i = bid * 256 + threadIdx.x;
    float4 v = ((const float4*)x)[i];
    ushort4 o;
    o.x = f2bf(v.x); o.y = f2bf(v.y); o.z = f2bf(v.z); o.w = f2bf(v.w);
    ((ushort4*)xb)[i] = o;
  } else if (bid < 8192) {  // weight transpose (+Q-path scale)
    const int u = bid - 4096;
    const int z = u >> 10, rem = u & 1023;
    const float* w = (z == 0) ? wq : (z == 1) ? wk : (z == 2) ? wv : wo;
    unsigned short* dst = (z < 3) ? (wqkvT + (size_t)z * 1024 * 1024) : woT;
    const float scale = (z == 0) ? 0.18033688011f : 1.0f;  // 0.125*log2(e)
    __shared__ float t[32][33];
    const int k0 = (rem & 31) * 32;
    const int n0 = (rem >> 5) * 32;
    const int tx = threadIdx.x & 31, ty = threadIdx.x >> 5;
#pragma unroll
    for (int i = 0; i < 32; i += 8)
      t[ty + i][tx] = w[(size_t)(k0 + ty + i) * 1024 + n0 + tx];
    __syncthreads();
#pragma unroll
    for (int i = 0; i < 32; i += 8)
      dst[(size_t)(n0 + ty + i) * 1024 + k0 + tx] = f2bf(t[tx][ty + i] * scale);
  } else {  // bias pack
    const int i = (bid - 8192) * 256 + threadIdx.x;
    float v;
    if (i < 1024) v = bq[i] * 0.18033688011f;
    else if (i < 2048) v = bk[i - 1024];
    else v = bv[i - 2048];
    bqkv[i] = v;
  }
}

// ---------------- GEMM 128^2 (m97 structure) — O-projection ----------------

template <typename OutT>
__global__ __launch_bounds__(256) void gemm_bt(
    const unsigned short* __restrict__ A, const unsigned short* __restrict__ Bt,
    const float* __restrict__ bias, OutT* __restrict__ C,
    int K, int ldc) {
  __shared__ unsigned short As[128 * 32];
  __shared__ unsigned short Bs[128 * 32];
  const int tid = threadIdx.x;
  const int lane = tid & 63;
  const int wave = tid >> 6;
  const int wm = (wave >> 1) * 64;
  const int wn = (wave & 1) * 64;
  const long bm = (long)blockIdx.x * 128;
  const long bn = (long)blockIdx.y * 128;

  const int sr = tid >> 2;
  const int sc = (tid & 3) * 8;
  const unsigned short* Ag0 = A + (bm + sr) * (long)K + sc;
  const unsigned short* Ag1 = A + (bm + 64 + sr) * (long)K + sc;
  const unsigned short* Bg0 = Bt + (bn + sr) * (long)K + sc;
  const unsigned short* Bg1 = Bt + (bn + 64 + sr) * (long)K + sc;
  unsigned short* As0 = &As[tid * 8];
  unsigned short* As1 = &As[2048 + tid * 8];
  unsigned short* Bs0 = &Bs[tid * 8];
  unsigned short* Bs1 = &Bs[2048 + tid * 8];

  f32x4 acc[4][4] = {};

  const int fr = lane & 15;
  const int fk = (lane >> 4) * 8;

  for (int kt = 0; kt < K; kt += 32) {
    gload_lds16(Ag0, As0);
    gload_lds16(Ag1, As1);
    gload_lds16(Bg0, Bs0);
    gload_lds16(Bg1, Bs1);
    Ag0 += 32; Ag1 += 32; Bg0 += 32; Bg1 += 32;
    __syncthreads();
    short8 af[4], bfv[4];
#pragma unroll
    for (int i = 0; i < 4; i++) af[i] = *(const short8*)&As[(wm + i * 16 + fr) * 32 + fk];
#pragma unroll
    for (int j = 0; j < 4; j++) bfv[j] = *(const short8*)&Bs[(wn + j * 16 + fr) * 32 + fk];
#pragma unroll
    for (int i = 0; i < 4; i++)
#pragma unroll
      for (int j = 0; j < 4; j++)
        acc[i][j] = __builtin_amdgcn_mfma_f32_16x16x32_bf16(af[i], bfv[j], acc[i][j], 0, 0, 0);
    __syncthreads();
  }

  const int crow = (lane >> 4) * 4;
  const int ccol = lane & 15;
#pragma unroll
  for (int j = 0; j < 4; j++) {
    const long col = bn + wn + j * 16 + ccol;
    const float bv = bias[col];
#pragma unroll
    for (int i = 0; i < 4; i++) {
#pragma unroll
      for (int r = 0; r < 4; r++) {
        const long row = bm + wm + i * 16 + crow + r;
        const float val = acc[i][j][r] + bv;
        if constexpr (__is_same(OutT, float)) C[row * ldc + col] = val;
        else                                  C[row * ldc + col] = f2bf(val);
      }
    }
  }
}

// ---------------- GEMM 256^2, BK=64, 8 waves, 8-phase counted-vmcnt ----------------

__global__ __launch_bounds__(512, 2) void gemm256(
    const unsigned short* __restrict__ A, const unsigned short* __restrict__ Bt,
    const float* __restrict__ bias, unsigned short* __restrict__ C, int ldc) {
  constexpr int K = 1024;
  __shared__ unsigned short Sab[2][2][16384];  // [buf][0=A,1=B][256*64]
  const int tid = threadIdx.x;
  const int lane = tid & 63;
  const int w = tid >> 6;
  const int wr = w >> 2, wc = w & 3;
  const long bm = (long)blockIdx.x * 256;
  const long bn = (long)blockIdx.y * 256;
  const int fr = lane & 15, fg = lane >> 4;

  const int srow = tid >> 3;  // 0..63
  const int kch = tid & 7;

  auto stage = [&](int o, int buf, int tk, int h) {
#pragma unroll
    for (int l = 0; l < 2; ++l) {
      const int rih = l * 64 + srow;
      const unsigned short* src = (o ? Bt : A) +
          ((o ? bn : bm) + h * 128 + rih) * (long)K + tk * 64 + ((kch ^ (rih & 7)) * 8);
      gload_lds16(src, &Sab[buf][o][h * 8192 + (l * 512 + tid) * 8]);
    }
  };

  f32x4 acc[8][4] = {};

  stage(0, 0, 0, 0); stage(0, 0, 0, 1);
  stage(1, 0, 0, 0); stage(1, 0, 0, 1);
  stage(1, 1, 1, 0); stage(1, 1, 1, 1);
  asm volatile("s_waitcnt vmcnt(4)" ::: "memory");
  __builtin_amdgcn_s_barrier();

  for (int it = 0; it < 8; ++it) {
    const int T = 2 * it;
    const int tkA = (T + 2 < 15) ? T + 2 : 15;
    const int tkB3 = (T + 3 < 15) ? T + 3 : 15;
#pragma unroll
    for (int half = 0; half < 2; ++half) {
      const int b = half;
      short8 bfr[4][2];
      short8 afr[2][2];
#pragma unroll
      for (int g = 0; g < 4; ++g) {
        if (g == 0) {
#pragma unroll
          for (int nj = 0; nj < 4; ++nj)
#pragma unroll
            for (int kc = 0; kc < 2; ++kc) {
              const int r = wc * 64 + nj * 16 + fr;
              bfr[nj][kc] = *(const short8*)&Sab[b][1][r * 64 + ((kc * 4 + fg) ^ (r & 7)) * 8];
            }
        }
#pragma unroll
        for (int mil = 0; mil < 2; ++mil)
#pragma unroll
          for (int kc = 0; kc < 2; ++kc) {
            const int r = wr * 128 + (2 * g + mil) * 16 + fr;
            afr[mil][kc] = *(const short8*)&Sab[b][0][r * 64 + ((kc * 4 + fg) ^ (r & 7)) * 8];
          }
        if (half == 0) {
          if (g == 0)      { stage(0, 1, T + 1, 0); stage(0, 1, T + 1, 1); }
          else if (g == 1) { stage(1, 0, tkA, 0); }
          else if (g == 2) { stage(1, 0, tkA, 1); }
        } else {
          if (g == 0)      { stage(0, 0, tkA, 0); stage(0, 0, tkA, 1); }
          else if (g == 1) { stage(1, 1, tkB3, 0); }
          else if (g == 2) { stage(1, 1, tkB3, 1); }
        }
        __builtin_amdgcn_s_barrier();
        asm volatile("s_waitcnt lgkmcnt(0)" ::: "memory");
        __builtin_amdgcn_sched_barrier(0);
        __builtin_amdgcn_s_setprio(1);
#pragma unroll
        for (int mil = 0; mil < 2; ++mil)
#pragma unroll
          for (int nj = 0; nj < 4; ++nj)
#pragma unroll
            for (int kc = 0; kc < 2; ++kc)
              acc[2 * g + mil][nj] = __builtin_amdgcn_mfma_f32_16x16x32_bf16(
                  afr[mil][kc], bfr[nj][kc], acc[2 * g + mil][nj], 0, 0, 0);
        __builtin_amdgcn_s_setprio(0);
        if (g == 3) asm volatile("s_waitcnt vmcnt(4)" ::: "memory");
        __builtin_amdgcn_s_barrier();
      }
    }
  }

  const int crow = fg * 4;
  const int ccol = fr;
#pragma unroll
  for (int nj = 0; nj < 4; ++nj) {
    const long col = bn + wc * 64 + nj * 16 + ccol;
    const float bv = bias[col];
#pragma unroll
    for (int mi = 0; mi < 8; ++mi)
#pragma unroll
      for (int r = 0; r < 4; ++r) {
        const long row = bm + wr * 128 + mi * 16 + crow + r;
        C[row * ldc + col] = f2bf(acc[mi][nj][r] + bv);
      }
  }
}

// ---------------- flash attention (v7: swapped QK^T, in-register P) ----------------
// sa = mfma(A=K, B=Q): lane holds P for q = fr. K A-fragment loaded with row-slot
// permutation kv(n,s) = (s>>2)*8 + n*4 + (s&3) so the lane's 8 outputs are exactly
// kv = fg*8+{0..7} -> P packs to the PV A-fragment with 4 cvt_pk, no cross-lane ops.
// Ps buffer GONE -> LDS 32768 = 5 blocks/CU. m,s scalars per (qi) at q=fr; softmax
// reduce = in-lane + shfl_xor(16,32). O lives at q'=fg*4+r (PV output layout);
// rescale factors cross q-layouts via __shfl on the rare defer-max trigger.

#define TRRD(d, o) asm volatile("ds_read_b64_tr_b16 %0, %1 offset:" o \
                                : "=v"(d) : "v"(vtr) : "memory")
#define LGKM(n) asm volatile("s_waitcnt lgkmcnt(" #n ")" ::: "memory")

__global__ __launch_bounds__(256, 5) void attn_fwd(
    const unsigned short* __restrict__ qkv, unsigned short* __restrict__ out) {
  __shared__ unsigned short Ks[2 * 4096];
  __shared__ unsigned short Vs[2 * 4096];
  const int tid = threadIdx.x;
  const int lane = tid & 63;
  const int w = tid >> 6;
  const int qh = w >> 1, kh = w & 1;

  const int xcd = blockIdx.x & 7, slot = blockIdx.x >> 3;
  const int pair = xcd * 4 + (slot >> 5);
  const int qtile = slot & 31;
  const int h = pair & 15, b = pair >> 4;
  const long rowbase = (long)b * 2048;
  const int hq = h * 64;
  const int fr = lane & 15;
  const int fg = lane >> 4;
  const int fk = fg * 8;
  const int q0 = qtile * 64 + qh * 32;

  // Q fragments (B operand; rows q0+qi*16+fr), pre-scaled by 0.125*log2e
  short8 qf[2][2];
#pragma unroll
  for (int qi = 0; qi < 2; qi++) {
    const long qr = rowbase + q0 + qi * 16 + fr;
    qf[qi][0] = *(const short8*)&qkv[qr * 3072 + hq + fk];
    qf[qi][1] = *(const short8*)&qkv[qr * 3072 + hq + 32 + fk];
  }

  // staging sources (unchanged from v6; both-sides XOR swizzle / tr-subtiled V)
  const int kr0 = tid >> 3, kr1 = 32 + (tid >> 3);
  const unsigned short* Kg0 = &qkv[(rowbase + kr0) * 3072 + 1024 + hq + (((tid & 7) ^ (kr0 & 7)) * 8)];
  const unsigned short* Kg1 = &qkv[(rowbase + kr1) * 3072 + 1024 + hq + (((tid & 7) ^ (kr1 & 7)) * 8)];
  const int vkv0 = ((tid >> 3) & 3) * 8 + ((tid >> 5) & 1) * 4 + ((tid >> 1) & 3);
  const int vd0 = ((tid >> 6) & 3) * 16 + (tid & 1) * 8;
  const unsigned short* Vg0 = &qkv[(rowbase + vkv0) * 3072 + 2048 + hq + vd0];
  const unsigned short* Vg1 = &qkv[(rowbase + vkv0 + 32) * 3072 + 2048 + hq + vd0];

  auto stage = [&](int buf) {
    gload_lds16(Kg0, &Ks[buf * 4096 + tid * 8]);
    gload_lds16(Kg1, &Ks[buf * 4096 + 2048 + tid * 8]);
    gload_lds16(Vg0, &Vs[buf * 4096 + tid * 8]);
    gload_lds16(Vg1, &Vs[buf * 4096 + 2048 + tid * 8]);
    Kg0 += 64 * 3072; Kg1 += 64 * 3072; Vg0 += 64 * 3072; Vg1 += 64 * 3072;
  };

  f32x4 o[2][4] = {};
  float m_[2] = {-1e30f, -1e30f};
  float s_[2] = {0.f, 0.f};

  // K A-fragment row-slot permutation: slot s=fr -> kv row within half
  const int krowbase = kh * 32 + (fr >> 2) * 8 + (fr & 3);  // + n*4

  stage(0);
  __syncthreads();

  for (int t = 0; t < 32; t++) {
    const int cur = t & 1;
    if (t < 31) stage(cur ^ 1);

    // QK^T swapped: sa[qi][n], lane = (q=fr, kv=fg*8+n*4+r)
    f32x4 sa[2][2];
    __builtin_amdgcn_s_setprio(1);
#pragma unroll
    for (int n = 0; n < 2; n++) {
      const int row = krowbase + n * 4;
      const short8 kf0 = *(const short8*)&Ks[cur * 4096 + ((row * 64 + fk) ^ ((row & 7) << 3))];
      const short8 kf1 = *(const short8*)&Ks[cur * 4096 + ((row * 64 + 32 + fk) ^ ((row & 7) << 3))];
#pragma unroll
      for (int qi = 0; qi < 2; qi++) {
        f32x4 z = {0.f, 0.f, 0.f, 0.f};
        z = __builtin_amdgcn_mfma_f32_16x16x32_bf16(kf0, qf[qi][0], z, 0, 0, 0);
        sa[qi][n] = __builtin_amdgcn_mfma_f32_16x16x32_bf16(kf1, qf[qi][1], z, 0, 0, 0);
      }
    }
    __builtin_amdgcn_s_setprio(0);

    // in-lane max per qi (8 values, q=fr)
    float lmax[2];
#pragma unroll
    for (int qi = 0; qi < 2; qi++)
      lmax[qi] = fmaxf(fmaxf(fmaxf(sa[qi][0][0], sa[qi][0][1]), fmaxf(sa[qi][0][2], sa[qi][0][3])),
                       fmaxf(fmaxf(sa[qi][1][0], sa[qi][1][1]), fmaxf(sa[qi][1][2], sa[qi][1][3])));
    // defer-max gate
    if (__any(fmaxf(lmax[0] - m_[0], lmax[1] - m_[1]) > 8.f)) {
#pragma unroll
      for (int qi = 0; qi < 2; qi++) {
        float mx = lmax[qi];
        mx = fmaxf(mx, __shfl_xor(mx, 16));
        mx = fmaxf(mx, __shfl_xor(mx, 32));
        const float nm = fmaxf(m_[qi], mx);
        const float fac = __builtin_amdgcn_exp2f(m_[qi] - nm);
        m_[qi] = nm;
        s_[qi] *= fac;
        // O lives at q'=fg*4+r: fetch fac from the lane owning that q-row
        float facp[4];
#pragma unroll
        for (int r = 0; r < 4; r++) facp[r] = __shfl(fac, fg * 4 + r);
#pragma unroll
        for (int dj = 0; dj < 4; dj++)
#pragma unroll
          for (int r = 0; r < 4; r++) o[qi][dj][r] *= facp[r];
      }
    }

    // P = exp2(sa - m), in-lane sum + pack to PV A-fragment
    short8 pa[2];
#pragma unroll
    for (int qi = 0; qi < 2; qi++) {
      float p[8];
#pragma unroll
      for (int n = 0; n < 2; n++)
#pragma unroll
        for (int r = 0; r < 4; r++)
          p[n * 4 + r] = __builtin_amdgcn_exp2f(sa[qi][n][r] - m_[qi]);
      float sl = ((p[0] + p[1]) + (p[2] + p[3])) + ((p[4] + p[5]) + (p[6] + p[7]));
      sl += __shfl_xor(sl, 16);
      sl += __shfl_xor(sl, 32);
      s_[qi] += sl;
      union { unsigned u[4]; short8 v; } pk;
      pk.u[0] = cvtpk_bf16(p[0], p[1]);
      pk.u[1] = cvtpk_bf16(p[2], p[3]);
      pk.u[2] = cvtpk_bf16(p[4], p[5]);
      pk.u[3] = cvtpk_bf16(p[6], p[7]);
      pa[qi] = pk.v;
    }

    // V^T fragments via HW transpose read (wave's kv half)
    const __attribute__((address_space(3))) unsigned short* vtr =
        (const __attribute__((address_space(3))) unsigned short*)&Vs[0] +
        cur * 4096 + kh * 2048 + lane * 4;
    short4v v0[4], v1[4];
    TRRD(v0[0], "0");    TRRD(v1[0], "512");
    TRRD(v0[1], "1024"); TRRD(v1[1], "1536");
    TRRD(v0[2], "2048"); TRRD(v1[2], "2560");
    TRRD(v0[3], "3072"); TRRD(v1[3], "3584");

    __builtin_amdgcn_s_setprio(1);
    LGKM(6); __builtin_amdgcn_sched_barrier(0);
    {
      short8 vf = __builtin_shufflevector(v0[0], v1[0], 0, 1, 2, 3, 4, 5, 6, 7);
      o[0][0] = __builtin_amdgcn_mfma_f32_16x16x32_bf16(pa[0], vf, o[0][0], 0, 0, 0);
      o[1][0] = __builtin_amdgcn_mfma_f32_16x16x32_bf16(pa[1], vf, o[1][0], 0, 0, 0);
    }
    LGKM(4); __builtin_amdgcn_sched_barrier(0);
    {
      short8 vf = __builtin_shufflevector(v0[1], v1[1], 0, 1, 2, 3, 4, 5, 6, 7);
      o[0][1] = __builtin_amdgcn_mfma_f32_16x16x32_bf16(pa[0], vf, o[0][1], 0, 0, 0);
      o[1][1] = __builtin_amdgcn_mfma_f32_16x16x32_bf16(pa[1], vf, o[1][1], 0, 0, 0);
    }
    LGKM(2); __builtin_amdgcn_sched_barrier(0);
    {
      short8 vf = __builtin_shufflevector(v0[2], v1[2], 0, 1, 2, 3, 4, 5, 6, 7);
      o[0][2] = __builtin_amdgcn_mfma_f32_16x16x32_bf16(pa[0], vf, o[0][2], 0, 0, 0);
      o[1][2] = __builtin_amdgcn_mfma_f32_16x16x32_bf16(pa[1], vf, o[1][2], 0, 0, 0);
    }
    LGKM(0); __builtin_amdgcn_sched_barrier(0);
    {
      short8 vf = __builtin_shufflevector(v0[3], v1[3], 0, 1, 2, 3, 4, 5, 6, 7);
      o[0][3] = __builtin_amdgcn_mfma_f32_16x16x32_bf16(pa[0], vf, o[0][3], 0, 0, 0);
      o[1][3] = __builtin_amdgcn_mfma_f32_16x16x32_bf16(pa[1], vf, o[1][3], 0, 0, 0);
    }
    __builtin_amdgcn_s_setprio(0);
    __syncthreads();
  }

  // -------- kv-half LSE merge (Ks/Vs retired) --------
  float* mo = (float*)&Ks[0];  // [qh][idx 0..31][lane]
  float* ms = (float*)&Vs[0];  // [kh][qh][qi][{m,s}][fr]
  __syncthreads();
  if (kh == 1) {
#pragma unroll
    for (int qi = 0; qi < 2; qi++)
#pragma unroll
      for (int dj = 0; dj < 4; dj++)
#pragma unroll
        for (int r = 0; r < 4; r++)
          mo[(qh * 32 + qi * 16 + dj * 4 + r) * 64 + lane] = o[qi][dj][r];
  }
  if (fg == 0) {
#pragma unroll
    for (int qi = 0; qi < 2; qi++) {
      ms[(((kh * 2 + qh) * 2 + qi) * 2 + 0) * 16 + fr] = m_[qi];
      ms[(((kh * 2 + qh) * 2 + qi) * 2 + 1) * 16 + fr] = s_[qi];
    }
  }
  __syncthreads();
  if (kh == 0) {
#pragma unroll
    for (int qi = 0; qi < 2; qi++) {
      float f0[4], f1[4], rs[4];
#pragma unroll
      for (int r = 0; r < 4; r++) {
        const int qp = fg * 4 + r;  // O's q-row within 16
        const float m0 = ms[(((0 * 2 + qh) * 2 + qi) * 2 + 0) * 16 + qp];
        const float s0 = ms[(((0 * 2 + qh) * 2 + qi) * 2 + 1) * 16 + qp];
        const float m1 = ms[(((1 * 2 + qh) * 2 + qi) * 2 + 0) * 16 + qp];
        const float s1 = ms[(((1 * 2 + qh) * 2 + qi) * 2 + 1) * 16 + qp];
        const float mstar = fmaxf(m0, m1);
        f0[r] = __builtin_amdgcn_exp2f(m0 - mstar);
        f1[r] = __builtin_amdgcn_exp2f(m1 - mstar);
        rs[r] = __builtin_amdgcn_rcpf(s0 * f0[r] + s1 * f1[r]);
      }
#pragma unroll
      for (int dj = 0; dj < 4; dj++)
#pragma unroll
        for (int r = 0; r < 4; r++) {
          const float o1 = mo[(qh * 32 + qi * 16 + dj * 4 + r) * 64 + lane];
          const float val = (o[qi][dj][r] * f0[r] + o1 * f1[r]) * rs[r];
          const long row = rowbase + q0 + qi * 16 + fg * 4 + r;
          out[row * 1024 + hq + dj * 16 + fr] = f2bf(val);
        }
    }
  }
}

// ---------------- host ----------------

extern "C" void kernel_launch(void* const* d_in, const int* in_sizes, int n_in,
                              void* d_out, int out_size, void* d_ws, size_t ws_size,
                              hipStream_t stream) {
  const float* x  = (const float*)d_in[0];
  const float* wq = (const float*)d_in[1];
  const float* bq = (const float*)d_in[2];
  const float* wk = (const float*)d_in[3];
  const float* bk = (const float*)d_in[4];
  const float* wv = (const float*)d_in[5];
  const float* bv = (const float*)d_in[6];
  const float* wo = (const float*)d_in[7];
  const float* bo = (const float*)d_in[8];

  char* ws = (char*)d_ws;
  unsigned short* xb    = (unsigned short*)(ws);                       // 8 MB  [4096][1024]
  unsigned short* wqkvT = (unsigned short*)(ws + (8ull  << 20));       // 6 MB  [3072][1024]
  unsigned short* woT   = (unsigned short*)(ws + (14ull << 20));       // 2 MB  [1024][1024]
  float*          bqkv  = (float*)         (ws + (16ull << 20));       // 12 KB [3072]
  unsigned short* qkv   = (unsigned short*)(ws + (17ull << 20));       // 24 MB [4096][3072]
  unsigned short* attn  = (unsigned short*)(ws + (41ull << 20));       // 8 MB  [4096][1024]

  prep<<<8204, 256, 0, stream>>>(x, wq, wk, wv, wo, bq, bk, bv, xb, wqkvT, woT, bqkv);

  gemm256<<<dim3(16, 12), 512, 0, stream>>>(xb, wqkvT, bqkv, qkv, 3072);

  attn_fwd<<<1024, 256, 0, stream>>>(qkv, attn);

  gemm_bt<float><<<dim3(32, 8), 256, 0, stream>>>(attn, woT, bo, (float*)d_out, 1024, 1024);
}

// Round 10
// 123.578 us; speedup vs baseline: 1.7754x; 1.0326x over previous
//
#include <hip/hip_runtime.h>

typedef __attribute__((ext_vector_type(8))) short short8;
typedef __attribute__((ext_vector_type(4))) short short4v;
typedef __attribute__((ext_vector_type(4))) float f32x4;

__device__ inline unsigned short f2bf(float f) {
  union { float f; unsigned int u; } v; v.f = f;
  unsigned int r = v.u + 0x7FFFu + ((v.u >> 16) & 1u);
  return (unsigned short)(r >> 16);
}

__device__ inline unsigned cvtpk_bf16(float lo, float hi) {
  unsigned r;
  asm("v_cvt_pk_bf16_f32 %0, %1, %2" : "=v"(r) : "v"(lo), "v"(hi));
  return r;
}

__device__ inline void gload_lds16(const void* g, void* l) {
  __builtin_amdgcn_global_load_lds(
      (const __attribute__((address_space(1))) unsigned int*)g,
      (__attribute__((address_space(3))) unsigned int*)l, 16, 0, 0);
}

// ---------------- fused prep: x->bf16 | 4x weight transpose | bias pack ----------------

__global__ __launch_bounds__(256) void prep(
    const float* __restrict__ x,
    const float* __restrict__ wq, const float* __restrict__ wk,
    const float* __restrict__ wv, const float* __restrict__ wo,
    const float* __restrict__ bq, const float* __restrict__ bk,
    const float* __restrict__ bv,
    unsigned short* __restrict__ xb, unsigned short* __restrict__ wqkvT,
    unsigned short* __restrict__ woT, float* __restrict__ bqkv) {
  const int bid = blockIdx.x;
  if (bid < 4096) {
    const int i = bid * 256 + threadIdx.x;
    float4 v = ((const float4*)x)[i];
    ushort4 o;
    o.x = f2bf(v.x); o.y = f2bf(v.y); o.z = f2bf(v.z); o.w = f2bf(v.w);
    ((ushort4*)xb)[i] = o;
  } else if (bid < 8192) {
    const int u = bid - 4096;
    const int z = u >> 10, rem = u & 1023;
    const float* w = (z == 0) ? wq : (z == 1) ? wk : (z == 2) ? wv : wo;
    unsigned short* dst = (z < 3) ? (wqkvT + (size_t)z * 1024 * 1024) : woT;
    const float scale = (z == 0) ? 0.18033688011f : 1.0f;  // 0.125*log2(e)
    __shared__ float t[32][33];
    const int k0 = (rem & 31) * 32;
    const int n0 = (rem >> 5) * 32;
    const int tx = threadIdx.x & 31, ty = threadIdx.x >> 5;
#pragma unroll
    for (int i = 0; i < 32; i += 8)
      t[ty + i][tx] = w[(size_t)(k0 + ty + i) * 1024 + n0 + tx];
    __syncthreads();
#pragma unroll
    for (int i = 0; i < 32; i += 8)
      dst[(size_t)(n0 + ty + i) * 1024 + k0 + tx] = f2bf(t[tx][ty + i] * scale);
  } else {
    const int i = (bid - 8192) * 256 + threadIdx.x;
    float v;
    if (i < 1024) v = bq[i] * 0.18033688011f;
    else if (i < 2048) v = bk[i - 1024];
    else v = bv[i - 2048];
    bqkv[i] = v;
  }
}

// ---------------- GEMM 64x128 tile (O-projection; 2 blocks/CU) ----------------

__global__ __launch_bounds__(256) void gemm_bt64(
    const unsigned short* __restrict__ A, const unsigned short* __restrict__ Bt,
    const float* __restrict__ bias, float* __restrict__ C, int K, int ldc) {
  __shared__ unsigned short As[64 * 32];
  __shared__ unsigned short Bs[128 * 32];
  const int tid = threadIdx.x;
  const int lane = tid & 63;
  const int wave = tid >> 6;
  const int wm = (wave >> 1) * 32;
  const int wn = (wave & 1) * 64;
  const long bm = (long)blockIdx.x * 64;
  const long bn = (long)blockIdx.y * 128;

  const int sr = tid >> 2;
  const int sc = (tid & 3) * 8;
  const unsigned short* Ag0 = A + (bm + sr) * (long)K + sc;
  const unsigned short* Bg0 = Bt + (bn + sr) * (long)K + sc;
  const unsigned short* Bg1 = Bt + (bn + 64 + sr) * (long)K + sc;
  unsigned short* As0 = &As[tid * 8];
  unsigned short* Bs0 = &Bs[tid * 8];
  unsigned short* Bs1 = &Bs[2048 + tid * 8];

  f32x4 acc[2][4] = {};

  const int fr = lane & 15;
  const int fk = (lane >> 4) * 8;

  for (int kt = 0; kt < K; kt += 32) {
    gload_lds16(Ag0, As0);
    gload_lds16(Bg0, Bs0);
    gload_lds16(Bg1, Bs1);
    Ag0 += 32; Bg0 += 32; Bg1 += 32;
    __syncthreads();
    short8 af[2], bfv[4];
#pragma unroll
    for (int i = 0; i < 2; i++) af[i] = *(const short8*)&As[(wm + i * 16 + fr) * 32 + fk];
#pragma unroll
    for (int j = 0; j < 4; j++) bfv[j] = *(const short8*)&Bs[(wn + j * 16 + fr) * 32 + fk];
#pragma unroll
    for (int i = 0; i < 2; i++)
#pragma unroll
      for (int j = 0; j < 4; j++)
        acc[i][j] = __builtin_amdgcn_mfma_f32_16x16x32_bf16(af[i], bfv[j], acc[i][j], 0, 0, 0);
    __syncthreads();
  }

  const int crow = (lane >> 4) * 4;
  const int ccol = lane & 15;
#pragma unroll
  for (int j = 0; j < 4; j++) {
    const long col = bn + wn + j * 16 + ccol;
    const float bv = bias[col];
#pragma unroll
    for (int i = 0; i < 2; i++)
#pragma unroll
      for (int r = 0; r < 4; r++) {
        const long row = bm + wm + i * 16 + crow + r;
        C[row * ldc + col] = acc[i][j][r] + bv;
      }
  }
}

// ---------------- GEMM 256^2, BK=64, 8 waves, 8-phase counted-vmcnt ----------------

__global__ __launch_bounds__(512, 2) void gemm256(
    const unsigned short* __restrict__ A, const unsigned short* __restrict__ Bt,
    const float* __restrict__ bias, unsigned short* __restrict__ C, int ldc) {
  constexpr int K = 1024;
  __shared__ unsigned short Sab[2][2][16384];  // [buf][0=A,1=B][256*64]
  const int tid = threadIdx.x;
  const int lane = tid & 63;
  const int w = tid >> 6;
  const int wr = w >> 2, wc = w & 3;
  const long bm = (long)blockIdx.x * 256;
  const long bn = (long)blockIdx.y * 256;
  const int fr = lane & 15, fg = lane >> 4;

  const int srow = tid >> 3;  // 0..63
  const int kch = tid & 7;

  auto stage = [&](int o, int buf, int tk, int h) {
#pragma unroll
    for (int l = 0; l < 2; ++l) {
      const int rih = l * 64 + srow;
      const unsigned short* src = (o ? Bt : A) +
          ((o ? bn : bm) + h * 128 + rih) * (long)K + tk * 64 + ((kch ^ (rih & 7)) * 8);
      gload_lds16(src, &Sab[buf][o][h * 8192 + (l * 512 + tid) * 8]);
    }
  };

  f32x4 acc[8][4] = {};

  stage(0, 0, 0, 0); stage(0, 0, 0, 1);
  stage(1, 0, 0, 0); stage(1, 0, 0, 1);
  stage(1, 1, 1, 0); stage(1, 1, 1, 1);
  asm volatile("s_waitcnt vmcnt(4)" ::: "memory");
  __builtin_amdgcn_s_barrier();

  for (int it = 0; it < 8; ++it) {
    const int T = 2 * it;
    const int tkA = (T + 2 < 15) ? T + 2 : 15;
    const int tkB3 = (T + 3 < 15) ? T + 3 : 15;
#pragma unroll
    for (int half = 0; half < 2; ++half) {
      const int b = half;
      short8 bfr[4][2];
      short8 afr[2][2];
#pragma unroll
      for (int g = 0; g < 4; ++g) {
        if (g == 0) {
#pragma unroll
          for (int nj = 0; nj < 4; ++nj)
#pragma unroll
            for (int kc = 0; kc < 2; ++kc) {
              const int r = wc * 64 + nj * 16 + fr;
              bfr[nj][kc] = *(const short8*)&Sab[b][1][r * 64 + ((kc * 4 + fg) ^ (r & 7)) * 8];
            }
        }
#pragma unroll
        for (int mil = 0; mil < 2; ++mil)
#pragma unroll
          for (int kc = 0; kc < 2; ++kc) {
            const int r = wr * 128 + (2 * g + mil) * 16 + fr;
            afr[mil][kc] = *(const short8*)&Sab[b][0][r * 64 + ((kc * 4 + fg) ^ (r & 7)) * 8];
          }
        if (half == 0) {
          if (g == 0)      { stage(0, 1, T + 1, 0); stage(0, 1, T + 1, 1); }
          else if (g == 1) { stage(1, 0, tkA, 0); }
          else if (g == 2) { stage(1, 0, tkA, 1); }
        } else {
          if (g == 0)      { stage(0, 0, tkA, 0); stage(0, 0, tkA, 1); }
          else if (g == 1) { stage(1, 1, tkB3, 0); }
          else if (g == 2) { stage(1, 1, tkB3, 1); }
        }
        __builtin_amdgcn_s_barrier();
        asm volatile("s_waitcnt lgkmcnt(0)" ::: "memory");
        __builtin_amdgcn_sched_barrier(0);
        __builtin_amdgcn_s_setprio(1);
#pragma unroll
        for (int mil = 0; mil < 2; ++mil)
#pragma unroll
          for (int nj = 0; nj < 4; ++nj)
#pragma unroll
            for (int kc = 0; kc < 2; ++kc)
              acc[2 * g + mil][nj] = __builtin_amdgcn_mfma_f32_16x16x32_bf16(
                  afr[mil][kc], bfr[nj][kc], acc[2 * g + mil][nj], 0, 0, 0);
        __builtin_amdgcn_s_setprio(0);
        if (g == 3) asm volatile("s_waitcnt vmcnt(4)" ::: "memory");
        __builtin_amdgcn_s_barrier();
      }
    }
  }

  const int crow = fg * 4;
  const int ccol = fr;
#pragma unroll
  for (int nj = 0; nj < 4; ++nj) {
    const long col = bn + wc * 64 + nj * 16 + ccol;
    const float bv = bias[col];
#pragma unroll
    for (int mi = 0; mi < 8; ++mi)
#pragma unroll
      for (int r = 0; r < 4; ++r) {
        const long row = bm + wr * 128 + mi * 16 + crow + r;
        C[row * ldc + col] = f2bf(acc[mi][nj][r] + bv);
      }
  }
}

// ---------------- flash attention (v9 = v7-passing + KSWZ only) ----------------
// Exact v7 structure (swapped QK^T, in-register P, in-lane f32 sum + shfl, v7 merge).
// Single change: K swizzle (row&7) -> KSWZ(row) = (row&3)|(((row>>3)&1)<<2) on BOTH
// sides (staging source chunk + kf read index). The permuted A-rows vary only in
// bits {0,1,3}; KSWZ spreads 16 lanes over 8 chunks (2-way = free) vs 4-way before.

#define KSWZ(row) (((row) & 3) | ((((row) >> 3) & 1) << 2))
#define TRRD(d, o) asm volatile("ds_read_b64_tr_b16 %0, %1 offset:" o \
                                : "=v"(d) : "v"(vtr) : "memory")
#define LGKM(n) asm volatile("s_waitcnt lgkmcnt(" #n ")" ::: "memory")

__global__ __launch_bounds__(256, 5) void attn_fwd(
    const unsigned short* __restrict__ qkv, unsigned short* __restrict__ out) {
  __shared__ unsigned short Ks[2 * 4096];
  __shared__ unsigned short Vs[2 * 4096];
  const int tid = threadIdx.x;
  const int lane = tid & 63;
  const int w = tid >> 6;
  const int qh = w >> 1, kh = w & 1;

  const int xcd = blockIdx.x & 7, slot = blockIdx.x >> 3;
  const int pair = xcd * 4 + (slot >> 5);
  const int qtile = slot & 31;
  const int h = pair & 15, b = pair >> 4;
  const long rowbase = (long)b * 2048;
  const int hq = h * 64;
  const int fr = lane & 15;
  const int fg = lane >> 4;
  const int fk = fg * 8;
  const int q0 = qtile * 64 + qh * 32;

  // Q fragments (B operand; rows q0+qi*16+fr), pre-scaled by 0.125*log2e
  short8 qf[2][2];
#pragma unroll
  for (int qi = 0; qi < 2; qi++) {
    const long qr = rowbase + q0 + qi * 16 + fr;
    qf[qi][0] = *(const short8*)&qkv[qr * 3072 + hq + fk];
    qf[qi][1] = *(const short8*)&qkv[qr * 3072 + hq + 32 + fk];
  }

  // K staging (KSWZ on source chunk; LDS dest linear); V subtiled for tr_read
  const int kr0 = tid >> 3, kr1 = 32 + (tid >> 3);
  const unsigned short* Kg0 = &qkv[(rowbase + kr0) * 3072 + 1024 + hq + (((tid & 7) ^ KSWZ(kr0)) * 8)];
  const unsigned short* Kg1 = &qkv[(rowbase + kr1) * 3072 + 1024 + hq + (((tid & 7) ^ KSWZ(kr1)) * 8)];
  const int vkv0 = ((tid >> 3) & 3) * 8 + ((tid >> 5) & 1) * 4 + ((tid >> 1) & 3);
  const int vd0 = ((tid >> 6) & 3) * 16 + (tid & 1) * 8;
  const unsigned short* Vg0 = &qkv[(rowbase + vkv0) * 3072 + 2048 + hq + vd0];
  const unsigned short* Vg1 = &qkv[(rowbase + vkv0 + 32) * 3072 + 2048 + hq + vd0];

  auto stage = [&](int buf) {
    gload_lds16(Kg0, &Ks[buf * 4096 + tid * 8]);
    gload_lds16(Kg1, &Ks[buf * 4096 + 2048 + tid * 8]);
    gload_lds16(Vg0, &Vs[buf * 4096 + tid * 8]);
    gload_lds16(Vg1, &Vs[buf * 4096 + 2048 + tid * 8]);
    Kg0 += 64 * 3072; Kg1 += 64 * 3072; Vg0 += 64 * 3072; Vg1 += 64 * 3072;
  };

  f32x4 o[2][4] = {};
  float m_[2] = {-1e30f, -1e30f};
  float s_[2] = {0.f, 0.f};

  // K A-fragment row-slot permutation: slot s=fr -> kv row within half
  const int krowbase = kh * 32 + (fr >> 2) * 8 + (fr & 3);  // + n*4

  stage(0);
  __syncthreads();

  for (int t = 0; t < 32; t++) {
    const int cur = t & 1;
    if (t < 31) stage(cur ^ 1);

    // QK^T swapped: sa[qi][n], lane = (q=fr, kv=fg*8+n*4+r)
    f32x4 sa[2][2];
    __builtin_amdgcn_s_setprio(1);
#pragma unroll
    for (int n = 0; n < 2; n++) {
      const int row = krowbase + n * 4;
      const short8 kf0 = *(const short8*)&Ks[cur * 4096 + ((row * 64 + fk) ^ (KSWZ(row) << 3))];
      const short8 kf1 = *(const short8*)&Ks[cur * 4096 + ((row * 64 + 32 + fk) ^ (KSWZ(row) << 3))];
#pragma unroll
      for (int qi = 0; qi < 2; qi++) {
        f32x4 z = {0.f, 0.f, 0.f, 0.f};
        z = __builtin_amdgcn_mfma_f32_16x16x32_bf16(kf0, qf[qi][0], z, 0, 0, 0);
        sa[qi][n] = __builtin_amdgcn_mfma_f32_16x16x32_bf16(kf1, qf[qi][1], z, 0, 0, 0);
      }
    }
    __builtin_amdgcn_s_setprio(0);

    // in-lane max per qi (8 values, q=fr)
    float lmax[2];
#pragma unroll
    for (int qi = 0; qi < 2; qi++)
      lmax[qi] = fmaxf(fmaxf(fmaxf(sa[qi][0][0], sa[qi][0][1]), fmaxf(sa[qi][0][2], sa[qi][0][3])),
                       fmaxf(fmaxf(sa[qi][1][0], sa[qi][1][1]), fmaxf(sa[qi][1][2], sa[qi][1][3])));
    // defer-max gate
    if (__any(fmaxf(lmax[0] - m_[0], lmax[1] - m_[1]) > 8.f)) {
#pragma unroll
      for (int qi = 0; qi < 2; qi++) {
        float mx = lmax[qi];
        mx = fmaxf(mx, __shfl_xor(mx, 16));
        mx = fmaxf(mx, __shfl_xor(mx, 32));
        const float nm = fmaxf(m_[qi], mx);
        const float fac = __builtin_amdgcn_exp2f(m_[qi] - nm);
        m_[qi] = nm;
        s_[qi] *= fac;
        // O lives at q'=fg*4+r: fetch fac from the lane owning that q-row
        float facp[4];
#pragma unroll
        for (int r = 0; r < 4; r++) facp[r] = __shfl(fac, fg * 4 + r);
#pragma unroll
        for (int dj = 0; dj < 4; dj++)
#pragma unroll
          for (int r = 0; r < 4; r++) o[qi][dj][r] *= facp[r];
      }
    }

    // P = exp2(sa - m), in-lane sum + pack to PV A-fragment
    short8 pa[2];
#pragma unroll
    for (int qi = 0; qi < 2; qi++) {
      float p[8];
#pragma unroll
      for (int n = 0; n < 2; n++)
#pragma unroll
        for (int r = 0; r < 4; r++)
          p[n * 4 + r] = __builtin_amdgcn_exp2f(sa[qi][n][r] - m_[qi]);
      float sl = ((p[0] + p[1]) + (p[2] + p[3])) + ((p[4] + p[5]) + (p[6] + p[7]));
      sl += __shfl_xor(sl, 16);
      sl += __shfl_xor(sl, 32);
      s_[qi] += sl;
      union { unsigned u[4]; short8 v; } pk;
      pk.u[0] = cvtpk_bf16(p[0], p[1]);
      pk.u[1] = cvtpk_bf16(p[2], p[3]);
      pk.u[2] = cvtpk_bf16(p[4], p[5]);
      pk.u[3] = cvtpk_bf16(p[6], p[7]);
      pa[qi] = pk.v;
    }

    // V^T fragments via HW transpose read (wave's kv half)
    const __attribute__((address_space(3))) unsigned short* vtr =
        (const __attribute__((address_space(3))) unsigned short*)&Vs[0] +
        cur * 4096 + kh * 2048 + lane * 4;
    short4v v0[4], v1[4];
    TRRD(v0[0], "0");    TRRD(v1[0], "512");
    TRRD(v0[1], "1024"); TRRD(v1[1], "1536");
    TRRD(v0[2], "2048"); TRRD(v1[2], "2560");
    TRRD(v0[3], "3072"); TRRD(v1[3], "3584");

    __builtin_amdgcn_s_setprio(1);
    LGKM(6); __builtin_amdgcn_sched_barrier(0);
    {
      short8 vf = __builtin_shufflevector(v0[0], v1[0], 0, 1, 2, 3, 4, 5, 6, 7);
      o[0][0] = __builtin_amdgcn_mfma_f32_16x16x32_bf16(pa[0], vf, o[0][0], 0, 0, 0);
      o[1][0] = __builtin_amdgcn_mfma_f32_16x16x32_bf16(pa[1], vf, o[1][0], 0, 0, 0);
    }
    LGKM(4); __builtin_amdgcn_sched_barrier(0);
    {
      short8 vf = __builtin_shufflevector(v0[1], v1[1], 0, 1, 2, 3, 4, 5, 6, 7);
      o[0][1] = __builtin_amdgcn_mfma_f32_16x16x32_bf16(pa[0], vf, o[0][1], 0, 0, 0);
      o[1][1] = __builtin_amdgcn_mfma_f32_16x16x32_bf16(pa[1], vf, o[1][1], 0, 0, 0);
    }
    LGKM(2); __builtin_amdgcn_sched_barrier(0);
    {
      short8 vf = __builtin_shufflevector(v0[2], v1[2], 0, 1, 2, 3, 4, 5, 6, 7);
      o[0][2] = __builtin_amdgcn_mfma_f32_16x16x32_bf16(pa[0], vf, o[0][2], 0, 0, 0);
      o[1][2] = __builtin_amdgcn_mfma_f32_16x16x32_bf16(pa[1], vf, o[1][2], 0, 0, 0);
    }
    LGKM(0); __builtin_amdgcn_sched_barrier(0);
    {
      short8 vf = __builtin_shufflevector(v0[3], v1[3], 0, 1, 2, 3, 4, 5, 6, 7);
      o[0][3] = __builtin_amdgcn_mfma_f32_16x16x32_bf16(pa[0], vf, o[0][3], 0, 0, 0);
      o[1][3] = __builtin_amdgcn_mfma_f32_16x16x32_bf16(pa[1], vf, o[1][3], 0, 0, 0);
    }
    __builtin_amdgcn_s_setprio(0);
    __syncthreads();
  }

  // -------- kv-half LSE merge (Ks/Vs retired; exact v7 layout) --------
  float* mo = (float*)&Ks[0];  // [qh][idx 0..31][lane]
  float* ms = (float*)&Vs[0];  // [kh][qh][qi][{m,s}][fr]
  __syncthreads();
  if (kh == 1) {
#pragma unroll
    for (int qi = 0; qi < 2; qi++)
#pragma unroll
      for (int dj = 0; dj < 4; dj++)
#pragma unroll
        for (int r = 0; r < 4; r++)
          mo[(qh * 32 + qi * 16 + dj * 4 + r) * 64 + lane] = o[qi][dj][r];
  }
  if (fg == 0) {
#pragma unroll
    for (int qi = 0; qi < 2; qi++) {
      ms[(((kh * 2 + qh) * 2 + qi) * 2 + 0) * 16 + fr] = m_[qi];
      ms[(((kh * 2 + qh) * 2 + qi) * 2 + 1) * 16 + fr] = s_[qi];
    }
  }
  __syncthreads();
  if (kh == 0) {
#pragma unroll
    for (int qi = 0; qi < 2; qi++) {
      float f0[4], f1[4], rs[4];
#pragma unroll
      for (int r = 0; r < 4; r++) {
        const int qp = fg * 4 + r;  // O's q-row within 16
        const float m0 = ms[(((0 * 2 + qh) * 2 + qi) * 2 + 0) * 16 + qp];
        const float s0 = ms[(((0 * 2 + qh) * 2 + qi) * 2 + 1) * 16 + qp];
        const float m1 = ms[(((1 * 2 + qh) * 2 + qi) * 2 + 0) * 16 + qp];
        const float s1 = ms[(((1 * 2 + qh) * 2 + qi) * 2 + 1) * 16 + qp];
        const float mstar = fmaxf(m0, m1);
        f0[r] = __builtin_amdgcn_exp2f(m0 - mstar);
        f1[r] = __builtin_amdgcn_exp2f(m1 - mstar);
        rs[r] = __builtin_amdgcn_rcpf(s0 * f0[r] + s1 * f1[r]);
      }
#pragma unroll
      for (int dj = 0; dj < 4; dj++)
#pragma unroll
        for (int r = 0; r < 4; r++) {
          const float o1 = mo[(qh * 32 + qi * 16 + dj * 4 + r) * 64 + lane];
          const float val = (o[qi][dj][r] * f0[r] + o1 * f1[r]) * rs[r];
          const long row = rowbase + q0 + qi * 16 + fg * 4 + r;
          out[row * 1024 + hq + dj * 16 + fr] = f2bf(val);
        }
    }
  }
}

// ---------------- host ----------------

extern "C" void kernel_launch(void* const* d_in, const int* in_sizes, int n_in,
                              void* d_out, int out_size, void* d_ws, size_t ws_size,
                              hipStream_t stream) {
  const float* x  = (const float*)d_in[0];
  const float* wq = (const float*)d_in[1];
  const float* bq = (const float*)d_in[2];
  const float* wk = (const float*)d_in[3];
  const float* bk = (const float*)d_in[4];
  const float* wv = (const float*)d_in[5];
  const float* bv = (const float*)d_in[6];
  const float* wo = (const float*)d_in[7];
  const float* bo = (const float*)d_in[8];

  char* ws = (char*)d_ws;
  unsigned short* xb    = (unsigned short*)(ws);                       // 8 MB  [4096][1024]
  unsigned short* wqkvT = (unsigned short*)(ws + (8ull  << 20));       // 6 MB  [3072][1024]
  unsigned short* woT   = (unsigned short*)(ws + (14ull << 20));       // 2 MB  [1024][1024]
  float*          bqkv  = (float*)         (ws + (16ull << 20));       // 12 KB [3072]
  unsigned short* qkv   = (unsigned short*)(ws + (17ull << 20));       // 24 MB [4096][3072]
  unsigned short* attn  = (unsigned short*)(ws + (41ull << 20));       // 8 MB  [4096][1024]

  prep<<<8204, 256, 0, stream>>>(x, wq, wk, wv, wo, bq, bk, bv, xb, wqkvT, woT, bqkv);

  gemm256<<<dim3(16, 12), 512, 0, stream>>>(xb, wqkvT, bqkv, qkv, 3072);

  attn_fwd<<<1024, 256, 0, stream>>>(qkv, attn);

  gemm_bt64<<<dim3(64, 8), 256, 0, stream>>>(attn, woT, bo, (float*)d_out, 1024, 1024);
}

// Round 11
// 118.036 us; speedup vs baseline: 1.8587x; 1.0470x over previous
//
#include <hip/hip_runtime.h>

typedef __attribute__((ext_vector_type(8))) short short8;
typedef __attribute__((ext_vector_type(4))) short short4v;
typedef __attribute__((ext_vector_type(4))) float f32x4;

__device__ inline unsigned short f2bf(float f) {
  union { float f; unsigned int u; } v; v.f = f;
  unsigned int r = v.u + 0x7FFFu + ((v.u >> 16) & 1u);
  return (unsigned short)(r >> 16);
}

__device__ inline unsigned cvtpk_bf16(float lo, float hi) {
  unsigned r;
  asm("v_cvt_pk_bf16_f32 %0, %1, %2" : "=v"(r) : "v"(lo), "v"(hi));
  return r;
}

__device__ inline void gload_lds16(const void* g, void* l) {
  __builtin_amdgcn_global_load_lds(
      (const __attribute__((address_space(1))) unsigned int*)g,
      (__attribute__((address_space(3))) unsigned int*)l, 16, 0, 0);
}

// ---------------- fused prep: x->bf16 | 4x weight transpose | bias pack ----------------

__global__ __launch_bounds__(256) void prep(
    const float* __restrict__ x,
    const float* __restrict__ wq, const float* __restrict__ wk,
    const float* __restrict__ wv, const float* __restrict__ wo,
    const float* __restrict__ bq, const float* __restrict__ bk,
    const float* __restrict__ bv,
    unsigned short* __restrict__ xb, unsigned short* __restrict__ wqkvT,
    unsigned short* __restrict__ woT, float* __restrict__ bqkv) {
  const int bid = blockIdx.x;
  if (bid < 4096) {
    const int i = bid * 256 + threadIdx.x;
    float4 v = ((const float4*)x)[i];
    ushort4 o;
    o.x = f2bf(v.x); o.y = f2bf(v.y); o.z = f2bf(v.z); o.w = f2bf(v.w);
    ((ushort4*)xb)[i] = o;
  } else if (bid < 8192) {
    const int u = bid - 4096;
    const int z = u >> 10, rem = u & 1023;
    const float* w = (z == 0) ? wq : (z == 1) ? wk : (z == 2) ? wv : wo;
    unsigned short* dst = (z < 3) ? (wqkvT + (size_t)z * 1024 * 1024) : woT;
    const float scale = (z == 0) ? 0.18033688011f : 1.0f;  // 0.125*log2(e)
    __shared__ float t[32][33];
    const int k0 = (rem & 31) * 32;
    const int n0 = (rem >> 5) * 32;
    const int tx = threadIdx.x & 31, ty = threadIdx.x >> 5;
#pragma unroll
    for (int i = 0; i < 32; i += 8)
      t[ty + i][tx] = w[(size_t)(k0 + ty + i) * 1024 + n0 + tx];
    __syncthreads();
#pragma unroll
    for (int i = 0; i < 32; i += 8)
      dst[(size_t)(n0 + ty + i) * 1024 + k0 + tx] = f2bf(t[tx][ty + i] * scale);
  } else {
    const int i = (bid - 8192) * 256 + threadIdx.x;
    float v;
    if (i < 1024) v = bq[i] * 0.18033688011f;
    else if (i < 2048) v = bk[i - 1024];
    else v = bv[i - 2048];
    bqkv[i] = v;
  }
}

// ---------------- GEMM 64x128 tile (O-projection; 2 blocks/CU) ----------------

__global__ __launch_bounds__(256) void gemm_bt64(
    const unsigned short* __restrict__ A, const unsigned short* __restrict__ Bt,
    const float* __restrict__ bias, float* __restrict__ C, int K, int ldc) {
  __shared__ unsigned short As[64 * 32];
  __shared__ unsigned short Bs[128 * 32];
  const int tid = threadIdx.x;
  const int lane = tid & 63;
  const int wave = tid >> 6;
  const int wm = (wave >> 1) * 32;
  const int wn = (wave & 1) * 64;
  const long bm = (long)blockIdx.x * 64;
  const long bn = (long)blockIdx.y * 128;

  const int sr = tid >> 2;
  const int sc = (tid & 3) * 8;
  const unsigned short* Ag0 = A + (bm + sr) * (long)K + sc;
  const unsigned short* Bg0 = Bt + (bn + sr) * (long)K + sc;
  const unsigned short* Bg1 = Bt + (bn + 64 + sr) * (long)K + sc;
  unsigned short* As0 = &As[tid * 8];
  unsigned short* Bs0 = &Bs[tid * 8];
  unsigned short* Bs1 = &Bs[2048 + tid * 8];

  f32x4 acc[2][4] = {};

  const int fr = lane & 15;
  const int fk = (lane >> 4) * 8;

  for (int kt = 0; kt < K; kt += 32) {
    gload_lds16(Ag0, As0);
    gload_lds16(Bg0, Bs0);
    gload_lds16(Bg1, Bs1);
    Ag0 += 32; Bg0 += 32; Bg1 += 32;
    __syncthreads();
    short8 af[2], bfv[4];
#pragma unroll
    for (int i = 0; i < 2; i++) af[i] = *(const short8*)&As[(wm + i * 16 + fr) * 32 + fk];
#pragma unroll
    for (int j = 0; j < 4; j++) bfv[j] = *(const short8*)&Bs[(wn + j * 16 + fr) * 32 + fk];
#pragma unroll
    for (int i = 0; i < 2; i++)
#pragma unroll
      for (int j = 0; j < 4; j++)
        acc[i][j] = __builtin_amdgcn_mfma_f32_16x16x32_bf16(af[i], bfv[j], acc[i][j], 0, 0, 0);
    __syncthreads();
  }

  const int crow = (lane >> 4) * 4;
  const int ccol = lane & 15;
#pragma unroll
  for (int j = 0; j < 4; j++) {
    const long col = bn + wn + j * 16 + ccol;
    const float bv = bias[col];
#pragma unroll
    for (int i = 0; i < 2; i++)
#pragma unroll
      for (int r = 0; r < 4; r++) {
        const long row = bm + wm + i * 16 + crow + r;
        C[row * ldc + col] = acc[i][j][r] + bv;
      }
  }
}

// ---------------- GEMM 256^2, BK=64, 8 waves, 8-phase counted-vmcnt ----------------

__global__ __launch_bounds__(512, 2) void gemm256(
    const unsigned short* __restrict__ A, const unsigned short* __restrict__ Bt,
    const float* __restrict__ bias, unsigned short* __restrict__ C, int ldc) {
  constexpr int K = 1024;
  __shared__ unsigned short Sab[2][2][16384];  // [buf][0=A,1=B][256*64]
  const int tid = threadIdx.x;
  const int lane = tid & 63;
  const int w = tid >> 6;
  const int wr = w >> 2, wc = w & 3;
  const long bm = (long)blockIdx.x * 256;
  const long bn = (long)blockIdx.y * 256;
  const int fr = lane & 15, fg = lane >> 4;

  const int srow = tid >> 3;  // 0..63
  const int kch = tid & 7;

  auto stage = [&](int o, int buf, int tk, int h) {
#pragma unroll
    for (int l = 0; l < 2; ++l) {
      const int rih = l * 64 + srow;
      const unsigned short* src = (o ? Bt : A) +
          ((o ? bn : bm) + h * 128 + rih) * (long)K + tk * 64 + ((kch ^ (rih & 7)) * 8);
      gload_lds16(src, &Sab[buf][o][h * 8192 + (l * 512 + tid) * 8]);
    }
  };

  f32x4 acc[8][4] = {};

  stage(0, 0, 0, 0); stage(0, 0, 0, 1);
  stage(1, 0, 0, 0); stage(1, 0, 0, 1);
  stage(1, 1, 1, 0); stage(1, 1, 1, 1);
  asm volatile("s_waitcnt vmcnt(4)" ::: "memory");
  __builtin_amdgcn_s_barrier();

  for (int it = 0; it < 8; ++it) {
    const int T = 2 * it;
    const int tkA = (T + 2 < 15) ? T + 2 : 15;
    const int tkB3 = (T + 3 < 15) ? T + 3 : 15;
#pragma unroll
    for (int half = 0; half < 2; ++half) {
      const int b = half;
      short8 bfr[4][2];
      short8 afr[2][2];
#pragma unroll
      for (int g = 0; g < 4; ++g) {
        if (g == 0) {
#pragma unroll
          for (int nj = 0; nj < 4; ++nj)
#pragma unroll
            for (int kc = 0; kc < 2; ++kc) {
              const int r = wc * 64 + nj * 16 + fr;
              bfr[nj][kc] = *(const short8*)&Sab[b][1][r * 64 + ((kc * 4 + fg) ^ (r & 7)) * 8];
            }
        }
#pragma unroll
        for (int mil = 0; mil < 2; ++mil)
#pragma unroll
          for (int kc = 0; kc < 2; ++kc) {
            const int r = wr * 128 + (2 * g + mil) * 16 + fr;
            afr[mil][kc] = *(const short8*)&Sab[b][0][r * 64 + ((kc * 4 + fg) ^ (r & 7)) * 8];
          }
        if (half == 0) {
          if (g == 0)      { stage(0, 1, T + 1, 0); stage(0, 1, T + 1, 1); }
          else if (g == 1) { stage(1, 0, tkA, 0); }
          else if (g == 2) { stage(1, 0, tkA, 1); }
        } else {
          if (g == 0)      { stage(0, 0, tkA, 0); stage(0, 0, tkA, 1); }
          else if (g == 1) { stage(1, 1, tkB3, 0); }
          else if (g == 2) { stage(1, 1, tkB3, 1); }
        }
        __builtin_amdgcn_s_barrier();
        asm volatile("s_waitcnt lgkmcnt(0)" ::: "memory");
        __builtin_amdgcn_sched_barrier(0);
        __builtin_amdgcn_s_setprio(1);
#pragma unroll
        for (int mil = 0; mil < 2; ++mil)
#pragma unroll
          for (int nj = 0; nj < 4; ++nj)
#pragma unroll
            for (int kc = 0; kc < 2; ++kc)
              acc[2 * g + mil][nj] = __builtin_amdgcn_mfma_f32_16x16x32_bf16(
                  afr[mil][kc], bfr[nj][kc], acc[2 * g + mil][nj], 0, 0, 0);
        __builtin_amdgcn_s_setprio(0);
        if (g == 3) asm volatile("s_waitcnt vmcnt(4)" ::: "memory");
        __builtin_amdgcn_s_barrier();
      }
    }
  }

  const int crow = fg * 4;
  const int ccol = fr;
#pragma unroll
  for (int nj = 0; nj < 4; ++nj) {
    const long col = bn + wc * 64 + nj * 16 + ccol;
    const float bv = bias[col];
#pragma unroll
    for (int mi = 0; mi < 8; ++mi)
#pragma unroll
      for (int r = 0; r < 4; ++r) {
        const long row = bm + wr * 128 + mi * 16 + crow + r;
        C[row * ldc + col] = f2bf(acc[mi][nj][r] + bv);
      }
  }
}

// ---------------- flash attention (v10: QBLK=128, 8 waves) ----------------
// v9's per-wave structure verbatim (swapped QK^T, in-register P, KSWZ, tr-read V).
// Change: 512 threads = 4 q-quarters x 2 kv-halves; each 16KB K/V stage +
// vmcnt drain + barrier now serves 2x the compute; K/V L2 traffic halves.
// Merge: qh extended to 0..3; o-dump fills the full retired 32KB K/V region,
// m/s in a separate 2KB array (LDS 34.8KB, 2 blocks/CU needed, 4 fit).

#define KSWZ(row) (((row) & 3) | ((((row) >> 3) & 1) << 2))
#define TRRD(d, o) asm volatile("ds_read_b64_tr_b16 %0, %1 offset:" o \
                                : "=v"(d) : "v"(vtr) : "memory")
#define LGKM(n) asm volatile("s_waitcnt lgkmcnt(" #n ")" ::: "memory")

__global__ __launch_bounds__(512, 4) void attn_fwd(
    const unsigned short* __restrict__ qkv, unsigned short* __restrict__ out) {
  __shared__ unsigned short S[4 * 4096];  // Ks = S[0..8191], Vs = S[8192..16383]
  __shared__ float msArr[512];
  unsigned short* Ks = &S[0];
  unsigned short* Vs = &S[8192];
  const int tid = threadIdx.x;
  const int lane = tid & 63;
  const int w = tid >> 6;
  const int qh = w >> 1, kh = w & 1;  // qh 0..3

  // 512 blocks: xcd = bid&7 owns 4 (b,h) pairs x 16 qtiles
  const int xcd = blockIdx.x & 7, slot = blockIdx.x >> 3;  // slot 0..63
  const int pair = xcd * 4 + (slot >> 4);                  // 0..31
  const int qtile = slot & 15;
  const int h = pair & 15, b = pair >> 4;
  const long rowbase = (long)b * 2048;
  const int hq = h * 64;
  const int fr = lane & 15;
  const int fg = lane >> 4;
  const int fk = fg * 8;
  const int q0 = qtile * 128 + qh * 32;

  // Q fragments (B operand; rows q0+qi*16+fr), pre-scaled by 0.125*log2e
  short8 qf[2][2];
#pragma unroll
  for (int qi = 0; qi < 2; qi++) {
    const long qr = rowbase + q0 + qi * 16 + fr;
    qf[qi][0] = *(const short8*)&qkv[qr * 3072 + hq + fk];
    qf[qi][1] = *(const short8*)&qkv[qr * 3072 + hq + 32 + fk];
  }

  // staging: 512 threads, 1 K-chunk + 1 V-chunk each (16KB/tile total)
  const int kr = tid >> 3;  // 0..63
  const unsigned short* Kg = &qkv[(rowbase + kr) * 3072 + 1024 + hq + (((tid & 7) ^ KSWZ(kr)) * 8)];
  const int vkv = ((tid >> 1) & 3) + ((tid >> 5) & 1) * 4 + ((tid >> 3) & 3) * 8 + ((tid >> 8) & 1) * 32;
  const int vd0 = (tid & 1) * 8 + ((tid >> 6) & 3) * 16;
  const unsigned short* Vg = &qkv[(rowbase + vkv) * 3072 + 2048 + hq + vd0];

  auto stage = [&](int buf) {
    gload_lds16(Kg, &Ks[buf * 4096 + tid * 8]);
    gload_lds16(Vg, &Vs[buf * 4096 + tid * 8]);
    Kg += 64 * 3072; Vg += 64 * 3072;
  };

  f32x4 o[2][4] = {};
  float m_[2] = {-1e30f, -1e30f};
  float s_[2] = {0.f, 0.f};

  // K A-fragment row-slot permutation: slot s=fr -> kv row within half
  const int krowbase = kh * 32 + (fr >> 2) * 8 + (fr & 3);  // + n*4

  stage(0);
  __syncthreads();

  for (int t = 0; t < 32; t++) {
    const int cur = t & 1;
    if (t < 31) stage(cur ^ 1);

    // QK^T swapped: sa[qi][n], lane = (q=fr, kv=fg*8+n*4+r)
    f32x4 sa[2][2];
    __builtin_amdgcn_s_setprio(1);
#pragma unroll
    for (int n = 0; n < 2; n++) {
      const int row = krowbase + n * 4;
      const short8 kf0 = *(const short8*)&Ks[cur * 4096 + ((row * 64 + fk) ^ (KSWZ(row) << 3))];
      const short8 kf1 = *(const short8*)&Ks[cur * 4096 + ((row * 64 + 32 + fk) ^ (KSWZ(row) << 3))];
#pragma unroll
      for (int qi = 0; qi < 2; qi++) {
        f32x4 z = {0.f, 0.f, 0.f, 0.f};
        z = __builtin_amdgcn_mfma_f32_16x16x32_bf16(kf0, qf[qi][0], z, 0, 0, 0);
        sa[qi][n] = __builtin_amdgcn_mfma_f32_16x16x32_bf16(kf1, qf[qi][1], z, 0, 0, 0);
      }
    }
    __builtin_amdgcn_s_setprio(0);

    // in-lane max per qi (8 values, q=fr)
    float lmax[2];
#pragma unroll
    for (int qi = 0; qi < 2; qi++)
      lmax[qi] = fmaxf(fmaxf(fmaxf(sa[qi][0][0], sa[qi][0][1]), fmaxf(sa[qi][0][2], sa[qi][0][3])),
                       fmaxf(fmaxf(sa[qi][1][0], sa[qi][1][1]), fmaxf(sa[qi][1][2], sa[qi][1][3])));
    // defer-max gate
    if (__any(fmaxf(lmax[0] - m_[0], lmax[1] - m_[1]) > 8.f)) {
#pragma unroll
      for (int qi = 0; qi < 2; qi++) {
        float mx = lmax[qi];
        mx = fmaxf(mx, __shfl_xor(mx, 16));
        mx = fmaxf(mx, __shfl_xor(mx, 32));
        const float nm = fmaxf(m_[qi], mx);
        const float fac = __builtin_amdgcn_exp2f(m_[qi] - nm);
        m_[qi] = nm;
        s_[qi] *= fac;
        // O lives at q'=fg*4+r: fetch fac from the lane owning that q-row
        float facp[4];
#pragma unroll
        for (int r = 0; r < 4; r++) facp[r] = __shfl(fac, fg * 4 + r);
#pragma unroll
        for (int dj = 0; dj < 4; dj++)
#pragma unroll
          for (int r = 0; r < 4; r++) o[qi][dj][r] *= facp[r];
      }
    }

    // P = exp2(sa - m), in-lane sum + pack to PV A-fragment
    short8 pa[2];
#pragma unroll
    for (int qi = 0; qi < 2; qi++) {
      float p[8];
#pragma unroll
      for (int n = 0; n < 2; n++)
#pragma unroll
        for (int r = 0; r < 4; r++)
          p[n * 4 + r] = __builtin_amdgcn_exp2f(sa[qi][n][r] - m_[qi]);
      float sl = ((p[0] + p[1]) + (p[2] + p[3])) + ((p[4] + p[5]) + (p[6] + p[7]));
      sl += __shfl_xor(sl, 16);
      sl += __shfl_xor(sl, 32);
      s_[qi] += sl;
      union { unsigned u[4]; short8 v; } pk;
      pk.u[0] = cvtpk_bf16(p[0], p[1]);
      pk.u[1] = cvtpk_bf16(p[2], p[3]);
      pk.u[2] = cvtpk_bf16(p[4], p[5]);
      pk.u[3] = cvtpk_bf16(p[6], p[7]);
      pa[qi] = pk.v;
    }

    // V^T fragments via HW transpose read (wave's kv half)
    const __attribute__((address_space(3))) unsigned short* vtr =
        (const __attribute__((address_space(3))) unsigned short*)&Vs[0] +
        cur * 4096 + kh * 2048 + lane * 4;
    short4v v0[4], v1[4];
    TRRD(v0[0], "0");    TRRD(v1[0], "512");
    TRRD(v0[1], "1024"); TRRD(v1[1], "1536");
    TRRD(v0[2], "2048"); TRRD(v1[2], "2560");
    TRRD(v0[3], "3072"); TRRD(v1[3], "3584");

    __builtin_amdgcn_s_setprio(1);
    LGKM(6); __builtin_amdgcn_sched_barrier(0);
    {
      short8 vf = __builtin_shufflevector(v0[0], v1[0], 0, 1, 2, 3, 4, 5, 6, 7);
      o[0][0] = __builtin_amdgcn_mfma_f32_16x16x32_bf16(pa[0], vf, o[0][0], 0, 0, 0);
      o[1][0] = __builtin_amdgcn_mfma_f32_16x16x32_bf16(pa[1], vf, o[1][0], 0, 0, 0);
    }
    LGKM(4); __builtin_amdgcn_sched_barrier(0);
    {
      short8 vf = __builtin_shufflevector(v0[1], v1[1], 0, 1, 2, 3, 4, 5, 6, 7);
      o[0][1] = __builtin_amdgcn_mfma_f32_16x16x32_bf16(pa[0], vf, o[0][1], 0, 0, 0);
      o[1][1] = __builtin_amdgcn_mfma_f32_16x16x32_bf16(pa[1], vf, o[1][1], 0, 0, 0);
    }
    LGKM(2); __builtin_amdgcn_sched_barrier(0);
    {
      short8 vf = __builtin_shufflevector(v0[2], v1[2], 0, 1, 2, 3, 4, 5, 6, 7);
      o[0][2] = __builtin_amdgcn_mfma_f32_16x16x32_bf16(pa[0], vf, o[0][2], 0, 0, 0);
      o[1][2] = __builtin_amdgcn_mfma_f32_16x16x32_bf16(pa[1], vf, o[1][2], 0, 0, 0);
    }
    LGKM(0); __builtin_amdgcn_sched_barrier(0);
    {
      short8 vf = __builtin_shufflevector(v0[3], v1[3], 0, 1, 2, 3, 4, 5, 6, 7);
      o[0][3] = __builtin_amdgcn_mfma_f32_16x16x32_bf16(pa[0], vf, o[0][3], 0, 0, 0);
      o[1][3] = __builtin_amdgcn_mfma_f32_16x16x32_bf16(pa[1], vf, o[1][3], 0, 0, 0);
    }
    __builtin_amdgcn_s_setprio(0);
    __syncthreads();
  }

  // -------- kv-half LSE merge (S retired; o-dump uses all 32KB) --------
  float* mo = (float*)&S[0];  // [qh 0..3][idx 0..31][lane] f32 = 32KB
  __syncthreads();
  if (kh == 1) {
#pragma unroll
    for (int qi = 0; qi < 2; qi++)
#pragma unroll
      for (int dj = 0; dj < 4; dj++)
#pragma unroll
        for (int r = 0; r < 4; r++)
          mo[(qh * 32 + qi * 16 + dj * 4 + r) * 64 + lane] = o[qi][dj][r];
  }
  if (fg == 0) {
#pragma unroll
    for (int qi = 0; qi < 2; qi++) {
      msArr[(((kh * 4 + qh) * 2 + qi) * 2 + 0) * 16 + fr] = m_[qi];
      msArr[(((kh * 4 + qh) * 2 + qi) * 2 + 1) * 16 + fr] = s_[qi];
    }
  }
  __syncthreads();
  if (kh == 0) {
#pragma unroll
    for (int qi = 0; qi < 2; qi++) {
      float f0[4], f1[4], rs[4];
#pragma unroll
      for (int r = 0; r < 4; r++) {
        const int qp = fg * 4 + r;  // O's q-row within 16
        const float m0 = msArr[(((0 * 4 + qh) * 2 + qi) * 2 + 0) * 16 + qp];
        const float s0 = msArr[(((0 * 4 + qh) * 2 + qi) * 2 + 1) * 16 + qp];
        const float m1 = msArr[(((1 * 4 + qh) * 2 + qi) * 2 + 0) * 16 + qp];
        const float s1 = msArr[(((1 * 4 + qh) * 2 + qi) * 2 + 1) * 16 + qp];
        const float mstar = fmaxf(m0, m1);
        f0[r] = __builtin_amdgcn_exp2f(m0 - mstar);
        f1[r] = __builtin_amdgcn_exp2f(m1 - mstar);
        rs[r] = __builtin_amdgcn_rcpf(s0 * f0[r] + s1 * f1[r]);
      }
#pragma unroll
      for (int dj = 0; dj < 4; dj++)
#pragma unroll
        for (int r = 0; r < 4; r++) {
          const float o1 = mo[(qh * 32 + qi * 16 + dj * 4 + r) * 64 + lane];
          const float val = (o[qi][dj][r] * f0[r] + o1 * f1[r]) * rs[r];
          const long row = rowbase + q0 + qi * 16 + fg * 4 + r;
          out[row * 1024 + hq + dj * 16 + fr] = f2bf(val);
        }
    }
  }
}

// ---------------- host ----------------

extern "C" void kernel_launch(void* const* d_in, const int* in_sizes, int n_in,
                              void* d_out, int out_size, void* d_ws, size_t ws_size,
                              hipStream_t stream) {
  const float* x  = (const float*)d_in[0];
  const float* wq = (const float*)d_in[1];
  const float* bq = (const float*)d_in[2];
  const float* wk = (const float*)d_in[3];
  const float* bk = (const float*)d_in[4];
  const float* wv = (const float*)d_in[5];
  const float* bv = (const float*)d_in[6];
  const float* wo = (const float*)d_in[7];
  const float* bo = (const float*)d_in[8];

  char* ws = (char*)d_ws;
  unsigned short* xb    = (unsigned short*)(ws);                       // 8 MB  [4096][1024]
  unsigned short* wqkvT = (unsigned short*)(ws + (8ull  << 20));       // 6 MB  [3072][1024]
  unsigned short* woT   = (unsigned short*)(ws + (14ull << 20));       // 2 MB  [1024][1024]
  float*          bqkv  = (float*)         (ws + (16ull << 20));       // 12 KB [3072]
  unsigned short* qkv   = (unsigned short*)(ws + (17ull << 20));       // 24 MB [4096][3072]
  unsigned short* attn  = (unsigned short*)(ws + (41ull << 20));       // 8 MB  [4096][1024]

  prep<<<8204, 256, 0, stream>>>(x, wq, wk, wv, wo, bq, bk, bv, xb, wqkvT, woT, bqkv);

  gemm256<<<dim3(16, 12), 512, 0, stream>>>(xb, wqkvT, bqkv, qkv, 3072);

  attn_fwd<<<512, 512, 0, stream>>>(qkv, attn);

  gemm_bt64<<<dim3(64, 8), 256, 0, stream>>>(attn, woT, bo, (float*)d_out, 1024, 1024);
}